// Round 17
// baseline (284.840 us; speedup 1.0000x reference)
//
#include <hip/hip_runtime.h>
#include <math.h>

namespace {
constexpr int B_ = 2, CIN = 8, H_ = 224, W_ = 224;
constexpr int K_ = 7;
constexpr int F_ = 64, E_ = 8;
constexpr int N1 = 43, N2 = 43, N_ = N1 * N2;   // 1849
constexpr int M_ = 49;                           // candidates per query
constexpr int D_ = 800;                          // patch dim (C*P*P)
constexpr int HW = H_ * W_;

// workspace layout (floats).
constexpr size_t FHW = (size_t)B_ * F_ * HW;     // 6,422,528
constexpr size_t OFF_H1E = 0;                    // h1 bf16 channels-last (ushort)
constexpr size_t OFF_H1T = OFF_H1E + FHW;
constexpr size_t OFF_H2E = OFF_H1T + FHW;        // channels-last bf16 hi/lo
constexpr size_t OFF_H2T = OFF_H2E + FHW;
constexpr size_t OFF_WK  = 0;                    // B*N*343 = 1,268,414 < FHW
constexpr size_t OFF_XCL = OFF_H1T;              // x channels-last, dead h1t half
constexpr size_t OFF_XE  = OFF_H2T + FHW;
constexpr size_t OFF_LTM = OFF_XE + (size_t)B_ * E_ * HW;
constexpr size_t OFF_PE  = OFF_LTM + (size_t)B_ * HW;
constexpr size_t OFF_LT  = OFF_PE + (size_t)B_ * N_ * D_;
constexpr size_t OFF_SQ  = OFF_LT + (size_t)B_ * N_;
constexpr int WPREP_N = 294912;   // conv2: 2br * 2kcb * 9idx * 4wv * 64lane * 8j
constexpr int WPREP1_N = 12288;   // conv1: 2br * 3ky * 4wv * 64lane * 8j
constexpr int WPREP3_N = 9216;    // conv3 per-set: 2kcb * 9idx * 64lane * 8j
constexpr int WPREP_TOT = WPREP_N + WPREP1_N + 2 * WPREP3_N;
// Savg: per-2x2-query-block averaged wk, padded 392 per cell.
constexpr int SAVG_N = B_ * 42 * 42 * 392;       // 1,382,976 < pe region

__device__ __forceinline__ int clampi(int v, int lo, int hi) {
  return min(max(v, lo), hi);
}

// bijective XCD-chunk swizzle (m204).
__device__ __forceinline__ int xcd_swz(int x, int nwg) {
  int xcd = x & 7, idx = x >> 3;
  int q = nwg >> 3, r = nwg & 7;
  int base = (xcd < r) ? xcd * (q + 1) : r * (q + 1) + (xcd - r) * q;
  return base + idx;
}

// round-to-nearest-even fp32 -> bf16
__device__ __forceinline__ unsigned short bf16_rne(float v) {
  unsigned u = __float_as_uint(v);
  return (unsigned short)((u + 0x7FFFu + ((u >> 16) & 1u)) >> 16);
}

typedef __attribute__((ext_vector_type(8))) short short8;
typedef __attribute__((ext_vector_type(4))) float float4v;
typedef __attribute__((ext_vector_type(2))) float float2v;
typedef __attribute__((ext_vector_type(4))) unsigned short ushort4v;
} // namespace

// ---------------------------------------------------------------------------
// Weight prep: conv2, conv1, conv3(e), conv3(t) bf16 hi/lo splits (unchanged).
// ---------------------------------------------------------------------------
__global__ __launch_bounds__(256) void wprep_k(
    const float* __restrict__ w_e, const float* __restrict__ w_t,
    const float* __restrict__ w1e, const float* __restrict__ w1t,
    const float* __restrict__ w3e, const float* __restrict__ w3t,
    unsigned short* __restrict__ whi, unsigned short* __restrict__ wlo,
    unsigned short* __restrict__ whi1, unsigned short* __restrict__ wlo1,
    unsigned short* __restrict__ whi3, unsigned short* __restrict__ wlo3) {
  int t = blockIdx.x * 256 + threadIdx.x;
  if (t >= WPREP_TOT) return;
  float v;
  unsigned short* dh;
  unsigned short* dl;
  int di;
  if (t < WPREP_N) {
    int j = t & 7;
    int lane = (t >> 3) & 63;
    int wv = (t >> 9) & 3;
    int t2 = t >> 11;
    int idx = t2 % 9;
    int t3 = t2 / 9;
    int kcb = t3 & 1;
    int br = t3 >> 1;
    const float* wgt = br ? w_t : w_e;
    int co = wv * 16 + (lane & 15);
    int ci = kcb * 32 + 8 * (lane >> 4) + j;
    v = wgt[((size_t)co * 64 + ci) * 9 + idx];
    dh = whi; dl = wlo; di = t;
  } else if (t < WPREP_N + WPREP1_N) {
    int t1 = t - WPREP_N;
    int j = t1 & 7;
    int lane = (t1 >> 3) & 63;
    int wv = (t1 >> 9) & 3;
    int t2 = t1 >> 11;
    int ky = t2 % 3;
    int br = t2 / 3;
    const float* wgt = br ? w1t : w1e;
    int co = wv * 16 + (lane & 15);
    int kx = lane >> 4;
    int ci = j;
    v = (kx < 3) ? wgt[(((size_t)co * 8 + ci) * 3 + ky) * 3 + kx] : 0.f;
    dh = whi1; dl = wlo1; di = t1;
  } else {
    int t3v = t - WPREP_N - WPREP1_N;          // [0, 2*9216)
    int set = t3v / WPREP3_N;                   // 0 = e, 1 = t
    int rem = t3v - set * WPREP3_N;
    int j = rem & 7;
    int lane = (rem >> 3) & 63;
    int t2 = rem >> 9;                          // 0..17
    int idx = t2 % 9;
    int kcb = t2 / 9;
    int co = lane & 15;
    int ci = kcb * 32 + 8 * (lane >> 4) + j;
    if (set == 0)
      v = (co < 8) ? w3e[((size_t)co * 64 + ci) * 9 + idx] : 0.f;
    else
      v = (co == 0) ? w3t[(size_t)ci * 9 + idx] : 0.f;
    dh = whi3; dl = wlo3; di = t3v;
  }
  unsigned u = __float_as_uint(v);
  unsigned short hi = (unsigned short)(u >> 16);
  float rem = v - __uint_as_float(u & 0xffff0000u);
  unsigned short lo = (unsigned short)(__float_as_uint(rem) >> 16);
  dh[di] = hi;
  dl[di] = lo;
}

// ---------------------------------------------------------------------------
// conv1 (8->64, relu) via MFMA bf16 3-term hi/lo split -> bf16-RNE
// channels-last output (unchanged from R23).
// ---------------------------------------------------------------------------
__global__ __launch_bounds__(256) void conv1_k(
    const float* __restrict__ x,
    const unsigned short* __restrict__ whi1, const unsigned short* __restrict__ wlo1,
    const float* __restrict__ b_e, unsigned short* __restrict__ o_e,
    const float* __restrict__ b_t, unsigned short* __restrict__ o_t) {
  const int tile = blockIdx.x;
  const int b = blockIdx.z & 1;
  const int br = blockIdx.z >> 1;
  const float* bias = br ? b_t : b_e;
  unsigned short* out = br ? o_t : o_e;

  const int th0 = (tile / 14) * 16, tw0 = (tile % 14) * 16;
  const int tid = threadIdx.x;
  const int wv = tid >> 6, lane = tid & 63;
  const int q = lane >> 4, n = lane & 15;

  __shared__ unsigned short sT[342 * 20];   // 18 rows x 19 cols x (8hi+8lo)

  const float* xB = x + (size_t)b * CIN * HW;
#pragma unroll
  for (int it = 0; it < 2; ++it) {
    int s = tid + 256 * it;
    if (s < 342) {
      int lr = s / 19, lc = s - lr * 19;
      int gh = th0 + lr - 1, gw = tw0 + lc - 1;
      short8 h8, l8;
#pragma unroll
      for (int ci = 0; ci < 8; ++ci) { h8[ci] = 0; l8[ci] = 0; }
      if (lc < 18 && gh >= 0 && gh < H_ && gw >= 0 && gw < W_) {
        const float* xp = xB + (size_t)gh * W_ + gw;
#pragma unroll
        for (int ci = 0; ci < 8; ++ci) {
          float v = xp[(size_t)ci * HW];
          unsigned u = __float_as_uint(v);
          float rem = v - __uint_as_float(u & 0xffff0000u);
          h8[ci] = (short)(u >> 16);
          l8[ci] = (short)(__float_as_uint(rem) >> 16);
        }
      }
      *(short8*)&sT[s * 20] = h8;
      *(short8*)&sT[s * 20 + 8] = l8;
    }
  }

  const short8* wh8 = (const short8*)whi1;
  const short8* wl8 = (const short8*)wlo1;
  short8 Ah[3], Al[3];
#pragma unroll
  for (int ky = 0; ky < 3; ++ky) {
    int ab = ((br * 3 + ky) * 4 + wv) * 64 + lane;
    Ah[ky] = wh8[ab];
    Al[ky] = wl8[ab];
  }

  float4v acc[16];
#pragma unroll
  for (int pr = 0; pr < 16; ++pr) acc[pr] = (float4v)0.f;

  __syncthreads();

#pragma unroll
  for (int r = 0; r < 18; ++r) {
    const unsigned short* p = &sT[(r * 19 + n + q) * 20];
    short8 Bh = *(const short8*)p;
    short8 Bl = *(const short8*)(p + 8);
#pragma unroll
    for (int ky = 0; ky < 3; ++ky) {
      const int pr = r - ky;
      if (pr >= 0 && pr < 16) {
        acc[pr] = __builtin_amdgcn_mfma_f32_16x16x32_bf16(Ah[ky], Bh, acc[pr], 0, 0, 0);
        acc[pr] = __builtin_amdgcn_mfma_f32_16x16x32_bf16(Al[ky], Bh, acc[pr], 0, 0, 0);
        acc[pr] = __builtin_amdgcn_mfma_f32_16x16x32_bf16(Ah[ky], Bl, acc[pr], 0, 0, 0);
      }
    }
  }

  float4v bv = *(const float4v*)&bias[wv * 16 + 4 * q];
#pragma unroll
  for (int pr = 0; pr < 16; ++pr) {
    ushort4v hv;
#pragma unroll
    for (int r = 0; r < 4; ++r)
      hv[r] = bf16_rne(fmaxf(acc[pr][r] + bv[r], 0.f));
    *(ushort4v*)&out[(((size_t)b * H_ + th0 + pr) * W_ + tw0 + n) * 64 + wv * 16 + 4 * q] = hv;
  }
}

// ---------------------------------------------------------------------------
// conv2 (64->64, relu) via MFMA, bf16 input 2-term (unchanged from R23).
// ---------------------------------------------------------------------------
__global__ __launch_bounds__(256) void conv2_mfma_k(
    const unsigned short* __restrict__ in_e, const unsigned short* __restrict__ in_t,
    const unsigned short* __restrict__ whi, const unsigned short* __restrict__ wlo,
    const float* __restrict__ b_e, const float* __restrict__ b_t,
    unsigned short* __restrict__ ehi, unsigned short* __restrict__ elo,
    unsigned short* __restrict__ thi, unsigned short* __restrict__ tlo) {
  constexpr int NLD = 12;                       // ceil(2880/256)
  const int tile = blockIdx.x;                  // 28 x 14
  const int b = blockIdx.z & 1;
  const int br = blockIdx.z >> 1;
  const unsigned short* in = br ? in_t : in_e;
  const float* bias = br ? b_t : b_e;
  unsigned short* ohi = br ? thi : ehi;
  unsigned short* olo = br ? tlo : elo;

  const int th0 = (tile / 14) * 8, tw0 = (tile % 14) * 16;
  const int tid = threadIdx.x;
  const int wv = tid >> 6, lane = tid & 63;
  const int q = lane >> 4, n = lane & 15;

  __shared__ unsigned short sT[2 * 128 * 68];
  unsigned* sT32 = (unsigned*)sT;

  float4v acc[8];
#pragma unroll
  for (int pr = 0; pr < 8; ++pr) acc[pr] = (float4v)0.f;

  const unsigned short* inB = in + (size_t)b * HW * 64;
  const short8* whi8 = (const short8*)whi;
  const short8* wlo8 = (const short8*)wlo;

  int po[NLD];
  unsigned okm = 0;
#pragma unroll
  for (int j = 0; j < NLD; ++j) {
    int s = tid + 256 * j;
    int sp = s >> 4, cp = s & 15;
    int lr = sp / 18, lc = sp - lr * 18;
    int gh = th0 + lr - 1, gw = tw0 + lc - 1;
    bool ok = (s < 2880) && gh >= 0 && gh < H_ && gw >= 0 && gw < W_;
    po[j] = ok ? (gh * W_ + gw) * 64 + 2 * cp : 0;   // ushort units
    if (ok) okm |= (1u << j);
  }

  for (int kcb = 0; kcb < 2; ++kcb) {
    unsigned stg[NLD];
#pragma unroll
    for (int j = 0; j < NLD; ++j)
      stg[j] = *(const unsigned*)&inB[(size_t)po[j] + kcb * 32];

    __syncthreads();
#pragma unroll
    for (int j = 0; j < NLD; ++j) {
      int s = tid + 256 * j;
      if (s < 2880) {
        int sp = s >> 4, cp = s & 15;
        sT32[sp * 18 + cp] = ((okm >> j) & 1) ? stg[j] : 0u;
      }
    }
    __syncthreads();

    short8 Ah[9], Al[9];
    const int abase = (((br * 2 + kcb) * 9) * 4 + wv) * 64 + lane;
#pragma unroll
    for (int idx = 0; idx < 9; ++idx) {
      Ah[idx] = whi8[abase + idx * 256];
      Al[idx] = wlo8[abase + idx * 256];
    }

#pragma unroll
    for (int r = 0; r < 10; ++r) {
      short8 Bh[3];
#pragma unroll
      for (int kx = 0; kx < 3; ++kx)
        Bh[kx] = *(const short8*)&sT[(r * 18 + n + kx) * 36 + 8 * q];
#pragma unroll
      for (int ky = 0; ky < 3; ++ky) {
        const int pr = r - ky;
        if (pr >= 0 && pr < 8) {
#pragma unroll
          for (int kx = 0; kx < 3; ++kx) {
            const int idx = ky * 3 + kx;
            acc[pr] = __builtin_amdgcn_mfma_f32_16x16x32_bf16(Ah[idx], Bh[kx], acc[pr], 0, 0, 0);
            acc[pr] = __builtin_amdgcn_mfma_f32_16x16x32_bf16(Al[idx], Bh[kx], acc[pr], 0, 0, 0);
          }
        }
      }
    }
  }

  // ---- epilogue: bias+relu -> hi/lo, LDS transpose, dense stores ----
  float4v bv = *(const float4v*)&bias[wv * 16 + 4 * q];
  unsigned short* sHi = (unsigned short*)sT;     // [128][68]
  unsigned short* sLo = sHi + 128 * 68;
  __syncthreads();                               // all sT MFMA reads done
#pragma unroll
  for (int pr = 0; pr < 8; ++pr) {
    int px = pr * 16 + n;
    ushort4v hv, lv;
#pragma unroll
    for (int r = 0; r < 4; ++r) {
      float v = fmaxf(acc[pr][r] + bv[r], 0.f);
      unsigned u = __float_as_uint(v);
      float rem = v - __uint_as_float(u & 0xffff0000u);
      hv[r] = (unsigned short)(u >> 16);
      lv[r] = (unsigned short)(__float_as_uint(rem) >> 16);
    }
    *(ushort4v*)&sHi[px * 68 + wv * 16 + 4 * q] = hv;
    *(ushort4v*)&sLo[px * 68 + wv * 16 + 4 * q] = lv;
  }
  __syncthreads();
#pragma unroll
  for (int i = 0; i < 4; ++i) {
    int f = tid + 256 * i;
    int px = f >> 3, c8 = f & 7;
    int h = th0 + (px >> 4), w = tw0 + (px & 15);
    size_t o = ((size_t)(b * H_ + h) * W_ + w) * 64 + c8 * 8;
    *(short8*)&ohi[o] = *(const short8*)&sHi[px * 68 + c8 * 8];
    *(short8*)&olo[o] = *(const short8*)&sLo[px * 68 + c8 * 8];
  }
}

// ---------------------------------------------------------------------------
// conv3 via MFMA — R14 form (unchanged).
// ---------------------------------------------------------------------------
__global__ __launch_bounds__(256) void conv3_mfma_k(
    const unsigned short* __restrict__ h2ehi, const unsigned short* __restrict__ h2elo,
    const unsigned short* __restrict__ h2thi, const unsigned short* __restrict__ h2tlo,
    const unsigned short* __restrict__ whi3, const unsigned short* __restrict__ wlo3,
    const float* __restrict__ b3e, const float* __restrict__ b3t,
    float* __restrict__ xe, float* __restrict__ ltm) {
  constexpr int NLD = 12;                       // ceil(2880/256)
  const int tile = blockIdx.x;                  // 28 x 14
  const int b = blockIdx.z & 1;
  const int br = blockIdx.z >> 1;
  const unsigned short* ihi = (br ? h2thi : h2ehi) + (size_t)b * HW * 64;
  const unsigned short* ilo = (br ? h2tlo : h2elo) + (size_t)b * HW * 64;

  const int th0 = (tile / 14) * 8, tw0 = (tile % 14) * 16;
  const int tid = threadIdx.x;
  const int wv = tid >> 6, lane = tid & 63;
  const int q = lane >> 4, n = lane & 15;

  __shared__ unsigned short sT[180 * 72];       // 10x18 px, 25920 B
  unsigned* sT32 = (unsigned*)sT;

  int po[NLD];
  unsigned okm = 0;
#pragma unroll
  for (int j = 0; j < NLD; ++j) {
    int s = tid + 256 * j;
    int sp = s >> 4, cp = s & 15;
    int lr = sp / 18, lc = sp - lr * 18;
    int gh = th0 + lr - 1, gw = tw0 + lc - 1;
    bool ok = (s < 2880) && gh >= 0 && gh < H_ && gw >= 0 && gw < W_;
    po[j] = ok ? (gh * W_ + gw) * 64 + 2 * cp : 0;
    if (ok) okm |= (1u << j);
  }

  const short8* wh8 = (const short8*)whi3;
  const short8* wl8 = (const short8*)wlo3;
  const int brBase = br * 1152;                 // set stride in short8 units

  float4v acc[2];
  acc[0] = (float4v)0.f;
  acc[1] = (float4v)0.f;

  for (int kcb = 0; kcb < 2; ++kcb) {
    unsigned sgh[NLD], sgl[NLD];
#pragma unroll
    for (int j = 0; j < NLD; ++j) {
      sgh[j] = *(const unsigned*)&ihi[(size_t)po[j] + kcb * 32];
      sgl[j] = *(const unsigned*)&ilo[(size_t)po[j] + kcb * 32];
    }
    __syncthreads();
#pragma unroll
    for (int j = 0; j < NLD; ++j) {
      int s = tid + 256 * j;
      if (s < 2880) {
        int sp = s >> 4, cp = s & 15;
        bool ok = (okm >> j) & 1;
        sT32[sp * 36 + cp] = ok ? sgh[j] : 0u;
        sT32[sp * 36 + 16 + cp] = ok ? sgl[j] : 0u;
      }
    }
    __syncthreads();

    short8 Ah[9], Al[9];
#pragma unroll
    for (int idx = 0; idx < 9; ++idx) {
      int fe = brBase + (kcb * 9 + idx) * 64 + lane;
      Ah[idx] = wh8[fe];
      Al[idx] = wl8[fe];
    }

#pragma unroll
    for (int r = 0; r < 4; ++r) {
      const int rr = 2 * wv + r;
      short8 Bh[3], Bl[3];
#pragma unroll
      for (int kx = 0; kx < 3; ++kx) {
        const unsigned short* p = &sT[(rr * 18 + n + kx) * 72 + 8 * q];
        Bh[kx] = *(const short8*)p;
        Bl[kx] = *(const short8*)(p + 32);
      }
#pragma unroll
      for (int ky = 0; ky < 3; ++ky) {
        const int pl = r - ky;
        if (pl >= 0 && pl < 2) {
#pragma unroll
          for (int kx = 0; kx < 3; ++kx) {
            const int idx = ky * 3 + kx;
            acc[pl] = __builtin_amdgcn_mfma_f32_16x16x32_bf16(Ah[idx], Bh[kx], acc[pl], 0, 0, 0);
            acc[pl] = __builtin_amdgcn_mfma_f32_16x16x32_bf16(Al[idx], Bh[kx], acc[pl], 0, 0, 0);
            acc[pl] = __builtin_amdgcn_mfma_f32_16x16x32_bf16(Ah[idx], Bl[kx], acc[pl], 0, 0, 0);
          }
        }
      }
    }
  }

  if (br == 0) {
    if (q < 2) {                                // co = 4q+r in [0,8)
      float4v bv = *(const float4v*)&b3e[4 * q];
#pragma unroll
      for (int pl = 0; pl < 2; ++pl) {
        int h = th0 + 2 * wv + pl;
#pragma unroll
        for (int r = 0; r < 4; ++r)
          xe[((size_t)(b * 8 + 4 * q + r) * H_ + h) * W_ + tw0 + n] = acc[pl][r] + bv[r];
      }
    }
  } else {
    if (q == 0) {                               // co 0 = log_temp
      float bt = b3t[0];
#pragma unroll
      for (int pl = 0; pl < 2; ++pl) {
        int h = th0 + 2 * wv + pl;
        ltm[(size_t)b * HW + h * W_ + tw0 + n] = acc[pl][0] + bt;
      }
    }
  }
}

// ---------------------------------------------------------------------------
// xcl: pack x (NCHW) to channels-last [b][pix][8] (dead h1t region).
// ---------------------------------------------------------------------------
__global__ __launch_bounds__(256) void xcl_k(const float* __restrict__ x,
                                             float* __restrict__ xcl) {
  int i = blockIdx.x * 256 + threadIdx.x;
  if (i >= B_ * HW) return;
  int b = i / HW, pix = i % HW;
  const float* xp = x + (size_t)b * CIN * HW + pix;
  float4v v0, v1;
#pragma unroll
  for (int c = 0; c < 4; ++c) v0[c] = xp[(size_t)c * HW];
#pragma unroll
  for (int c = 0; c < 4; ++c) v1[c] = xp[(size_t)(4 + c) * HW];
  *(float4v*)&xcl[(size_t)i * 8] = v0;
  *(float4v*)&xcl[(size_t)i * 8 + 4] = v1;
}

// ---------------------------------------------------------------------------
// prep: write pe row (from xe), reduce sq and lt (unchanged).
// ---------------------------------------------------------------------------
__global__ __launch_bounds__(256) void prep_k(const float* __restrict__ xe,
                                              const float* __restrict__ ltm,
                                              float* __restrict__ pe,
                                              float* __restrict__ lt,
                                              float* __restrict__ sq) {
  const int n = blockIdx.x, b = blockIdx.y;
  const int tid = threadIdx.x;
  const int wv = tid >> 6, lane = tid & 63;
  const int q1 = n / N2, q2 = n % N2;
  const int r0 = q1 * 5, c0 = q2 * 5;

  float s = 0.f;
  float* peR = pe + ((size_t)b * N_ + n) * D_;
#pragma unroll
  for (int j = 0; j < 4; ++j) {
    int d = tid + 256 * j;
    if (d < D_) {
      int c = d / 100;
      int rr = (d / 10) % 10;
      int cc = d % 10;
      size_t si = ((size_t)(b * 8 + c) * H_ + r0 + rr) * W_ + c0 + cc;
      float ve = xe[si];
      peR[d] = ve;
      s += ve * ve;
    }
  }
  float t = 0.f;
  if (tid < 100) t = ltm[(size_t)b * HW + (r0 + tid / 10) * W_ + c0 + tid % 10];

#pragma unroll
  for (int off = 32; off > 0; off >>= 1) {
    s += __shfl_xor(s, off);
    t += __shfl_xor(t, off);
  }
  __shared__ float rs[4], rt[4];
  if (lane == 0) { rs[wv] = s; rt[wv] = t; }
  __syncthreads();
  if (tid == 0) {
    sq[b * N_ + n] = rs[0] + rs[1] + rs[2] + rs[3];
    lt[b * N_ + n] = (rt[0] + rt[1] + rt[2] + rt[3]) * 0.01f;
  }
}

// ---------------------------------------------------------------------------
// attn stage 1 (unchanged).
// ---------------------------------------------------------------------------
__global__ __launch_bounds__(256) void attn_w_k(const float* __restrict__ pe,
                                                const float* __restrict__ lt,
                                                const float* __restrict__ sq,
                                                float* __restrict__ wk) {
  const int wv = threadIdx.x >> 6, lane = threadIdx.x & 63;
  const int ng = xcd_swz(blockIdx.x, (N_ + 3) / 4);
  const int n = ng * 4 + wv;
  if (n >= N_) return;
  const int b = blockIdx.y;
  const int q1 = n / N2, q2 = n % N2;

  const float* peB = pe + (size_t)b * N_ * D_;
  const float* qrow = peB + (size_t)n * D_;
  float q[13];
#pragma unroll
  for (int t = 0; t < 13; ++t) {
    int s = t * 64 + lane;
    q[t] = (s < D_) ? qrow[s] : 0.f;
  }

  const float sqn = sq[b * N_ + n];
  const float itemp = expf(-lt[b * N_ + n]);
  float gm = -INFINITY;

  for (int o1 = 0; o1 < 7; ++o1) {
    int c1 = clampi(q1 + o1 - 3, 0, N1 - 1);
    const float* rowb = peB + (size_t)(c1 * N2) * D_;
#pragma unroll
    for (int o2 = 0; o2 < 7; ++o2) {
      int c2 = clampi(q2 + o2 - 3, 0, N2 - 1);
      int cn = c1 * N2 + c2;
      const float* crow = rowb + (size_t)c2 * D_;
      float a = 0.f;
#pragma unroll
      for (int t = 0; t < 13; ++t) {
        float v;
        if (t < 12) v = crow[t * 64 + lane];
        else v = (lane < 32) ? crow[768 + lane] : 0.f;
        a += q[t] * v;
      }
#pragma unroll
      for (int off = 32; off > 0; off >>= 1) a += __shfl_xor(a, off);
      float Dv = -(sqn + sq[b * N_ + cn] - 2.f * a);
      float lg = (cn == n) ? -1e9f : Dv * itemp;
      const int m = o1 * 7 + o2;
      gm = (lane == m) ? lg : gm;
    }
  }

  float cur = (lane < M_) ? gm : -INFINITY;
  float* wrow = wk + (size_t)(b * N_ + n) * (M_ * K_);
#pragma unroll
  for (int k = 0; k < K_; ++k) {
    float mx = cur;
#pragma unroll
    for (int off = 32; off > 0; off >>= 1) mx = fmaxf(mx, __shfl_xor(mx, off));
    float e = (lane < M_) ? expf(cur - mx) : 0.f;
    float ssum = e;
#pragma unroll
    for (int off = 32; off > 0; off >>= 1) ssum += __shfl_xor(ssum, off);
    float w = e / ssum;
    if (lane < M_) wrow[lane * K_ + k] = w;
    cur += log1pf(-fminf(w, 1.f - 1e-6f));
  }
}

// ---------------------------------------------------------------------------
// savg (R24): per-2x2-query-block averaged wk, padded 8/m. Savg[b][42][42]
// [392]. Same sum order as R21's in-kernel version -> bitwise-identical.
// Lives in pe region (dead after attn_w).
// ---------------------------------------------------------------------------
__global__ __launch_bounds__(256) void savg_k(const float* __restrict__ wk,
                                              float* __restrict__ savg) {
  int i = blockIdx.x * 256 + threadIdx.x;
  if (i >= SAVG_N) return;
  int r = i % 392;
  int t = i / 392;
  int cl2 = t % 42;
  int t2 = t / 42;
  int cl1 = t2 % 42;
  int b = t2 / 42;
  int m = r >> 3, k = r & 7;
  float v = 0.f;
  if (k < 7) {
    size_t base = (size_t)(b * N_ + cl1 * N2 + cl2) * (M_ * K_) + m * 7 + k;
    v = 0.25f * (wk[base] + wk[base + M_ * K_] +
                 wk[base + (size_t)N2 * (M_ * K_)] +
                 wk[base + (size_t)(N2 + 1) * (M_ * K_)]);
  }
  savg[i] = v;
}

// ---------------------------------------------------------------------------
// foldpv R24: z split 4 ways (2 channels each) -> 1568 blocks (6.1/CU, LDS-
// capped 4/CU vs grid-capped 3 before); fast-path S staged from precomputed
// Savg (1 load/value vs 4 loads+3 adds). Numerics identical to R23.
// ---------------------------------------------------------------------------
__global__ __launch_bounds__(256) void foldpv_k(const float* __restrict__ xcl,
                                                const float* __restrict__ wk,
                                                const float* __restrict__ savg,
                                                float* __restrict__ out) {
  const int tile = xcd_swz(blockIdx.x, 196);
  const int b = blockIdx.y;
  const int c0 = blockIdx.z * 2;               // channels c0..c0+1
  const int t1 = tile / 14, t2 = tile % 14;
  const int ty0 = t1 * 16, tx0 = t2 * 16;
  const int tid = threadIdx.x;
  const int h = ty0 + (tid >> 4), w = tx0 + (tid & 15);
  const bool fast = (t1 >= 2 && t1 <= 11 && t2 >= 2 && t2 <= 11);

  __shared__ float smem[25 * 392];             // 39.2 KB (fast uses 16*392)

  const float* xclB = xcl + (size_t)b * HW * 8;
  const int pix = h * W_ + w;
  float* outB = out + (size_t)b * 64 * HW + pix;

  // x passthrough (2 channels per z)
  {
    float2v pv = *(const float2v*)&xclB[(size_t)pix * 8 + c0];
    outB[(size_t)c0 * HW] = pv[0];
    outB[(size_t)(c0 + 1) * HW] = pv[1];
  }

  float acc[2][7];
#pragma unroll
  for (int c = 0; c < 2; ++c)
#pragma unroll
    for (int k = 0; k < 7; ++k) acc[c][k] = 0.f;

  if (fast) {
    const int cl1_0 = (ty0 - 5) / 5, cl2_0 = (tx0 - 5) / 5;
    const float* sb = savg + (size_t)b * 42 * 42 * 392;
    for (int s = tid; s < 16 * 392; s += 256) {
      int cell = s / 392, r = s - cell * 392;
      int q1c = cl1_0 + (cell >> 2), q2c = cl2_0 + (cell & 3);
      smem[s] = sb[((size_t)q1c * 42 + q2c) * 392 + r];
    }
    __syncthreads();

    const int cl1 = (h - 5) / 5 - cl1_0, cl2 = (w - 5) / 5 - cl2_0;
    const float* sSp = smem + (cl1 * 4 + cl2) * 392;
    int roff[7], coff[7];
#pragma unroll
    for (int o = 0; o < 7; ++o) {
      roff[o] = (h + 5 * (o - 3)) * W_;
      coff[o] = w + 5 * (o - 3);
    }
#pragma unroll
    for (int o1 = 0; o1 < 7; ++o1) {
#pragma unroll
      for (int o2 = 0; o2 < 7; ++o2) {
        float2v xv = *(const float2v*)&xclB[((size_t)(roff[o1] + coff[o2])) * 8 + c0];
        const float* sp = sSp + (o1 * 7 + o2) * 8;
        float4v w4 = *(const float4v*)sp;
        float2v w2 = *(const float2v*)(sp + 4);
        float w6 = sp[6];
#pragma unroll
        for (int c = 0; c < 2; ++c) {
          acc[c][0] += w4[0] * xv[c];
          acc[c][1] += w4[1] * xv[c];
          acc[c][2] += w4[2] * xv[c];
          acc[c][3] += w4[3] * xv[c];
          acc[c][4] += w2[0] * xv[c];
          acc[c][5] += w2[1] * xv[c];
          acc[c][6] += w6 * xv[c];
        }
      }
    }
#pragma unroll
    for (int k = 0; k < 7; ++k)
#pragma unroll
      for (int c = 0; c < 2; ++c)
        outB[(size_t)(8 + k * 8 + c0 + c) * HW] = acc[c][k];
    return;
  }

  // ---- slow path ----
  const int q1lo_t = max(0, (ty0 - 5) / 5), q1hi_t = min(N1 - 1, (ty0 + 15) / 5);
  const int q2lo_t = max(0, (tx0 - 5) / 5), q2hi_t = min(N2 - 1, (tx0 + 15) / 5);
  const int nq1 = q1hi_t - q1lo_t + 1, nq2 = q2hi_t - q2lo_t + 1;

  {
    const int tot = nq1 * nq2 * 392;
    for (int s = tid; s < tot; s += 256) {
      int lq = s / 392, r = s - lq * 392;
      int m = r >> 3, k = r & 7;
      int n = (q1lo_t + lq / nq2) * N2 + (q2lo_t + lq % nq2);
      smem[s] = (k < 7) ? wk[(size_t)(b * N_ + n) * (M_ * K_) + m * 7 + k] : 0.f;
    }
  }
  __syncthreads();

  const int q1lo = max(0, (h - 5) / 5), q1hi = min(N1 - 1, h / 5);
  const int q2lo = max(0, (w - 5) / 5), q2hi = min(N2 - 1, w / 5);

  int cnt = 0;
  for (int q1 = q1lo; q1 <= q1hi; ++q1) {
    const int ib = h - 5 * q1;
    const int lq1 = q1 - q1lo_t;
    for (int q2 = q2lo; q2 <= q2hi; ++q2) {
      ++cnt;
      const int jb = w - 5 * q2;
      const float* wq = smem + (lq1 * nq2 + (q2 - q2lo_t)) * 392;
#pragma unroll
      for (int o1 = 0; o1 < 7; ++o1) {
        const int c1 = clampi(q1 + o1 - 3, 0, N1 - 1);
        const int row = c1 * 5 + ib;
#pragma unroll
        for (int o2 = 0; o2 < 7; ++o2) {
          const int c2 = clampi(q2 + o2 - 3, 0, N2 - 1);
          const int col = c2 * 5 + jb;
          float2v xv = *(const float2v*)&xclB[((size_t)row * W_ + col) * 8 + c0];
          const float* wp = wq + (o1 * 7 + o2) * 8;
          float4v w4 = *(const float4v*)wp;
          float2v w2 = *(const float2v*)(wp + 4);
          float w6 = wp[6];
#pragma unroll
          for (int c = 0; c < 2; ++c) {
            acc[c][0] += w4[0] * xv[c];
            acc[c][1] += w4[1] * xv[c];
            acc[c][2] += w4[2] * xv[c];
            acc[c][3] += w4[3] * xv[c];
            acc[c][4] += w2[0] * xv[c];
            acc[c][5] += w2[1] * xv[c];
            acc[c][6] += w6 * xv[c];
          }
        }
      }
    }
  }

  const float inv = (cnt > 0) ? 1.f / (float)cnt : 0.f;  // cnt in {0,1,2,4}
#pragma unroll
  for (int k = 0; k < 7; ++k)
#pragma unroll
    for (int c = 0; c < 2; ++c)
      outB[(size_t)(8 + k * 8 + c0 + c) * HW] = acc[c][k] * inv;
}

extern "C" void kernel_launch(void* const* d_in, const int* in_sizes, int n_in,
                              void* d_out, int out_size, void* d_ws,
                              size_t ws_size, hipStream_t stream) {
  const float* x   = (const float*)d_in[0];
  const float* w1e = (const float*)d_in[1];
  const float* b1e = (const float*)d_in[2];
  const float* w2e = (const float*)d_in[3];
  const float* b2e = (const float*)d_in[4];
  const float* w3e = (const float*)d_in[5];
  const float* b3e = (const float*)d_in[6];
  const float* w1t = (const float*)d_in[7];
  const float* b1t = (const float*)d_in[8];
  const float* w2t = (const float*)d_in[9];
  const float* b2t = (const float*)d_in[10];
  const float* w3t = (const float*)d_in[11];
  const float* b3t = (const float*)d_in[12];

  float* ws  = (float*)d_ws;
  float* out = (float*)d_out;

  unsigned short* h1e = (unsigned short*)(ws + OFF_H1E);   // bf16 channels-last
  unsigned short* h1t = (unsigned short*)(ws + OFF_H1T);
  unsigned short* h2ehi = (unsigned short*)(ws + OFF_H2E);   // channels-last hi/lo
  unsigned short* h2elo = h2ehi + (size_t)B_ * HW * 64;
  unsigned short* h2thi = (unsigned short*)(ws + OFF_H2T);
  unsigned short* h2tlo = h2thi + (size_t)B_ * HW * 64;
  float* wkb = ws + OFF_WK;
  float* xe  = ws + OFF_XE;
  float* ltm = ws + OFF_LTM;
  float* pe  = ws + OFF_PE;
  float* lt  = ws + OFF_LT;
  float* sqv = ws + OFF_SQ;
  unsigned short* whi  = (unsigned short*)(ws + OFF_XE);  // consumed before xe written
  unsigned short* wlo  = whi + WPREP_N;
  unsigned short* whi1 = wlo + WPREP_N;
  unsigned short* wlo1 = whi1 + WPREP1_N;
  unsigned short* whi3 = (unsigned short*)(ws + OFF_PE);  // consumed before pe written
  unsigned short* wlo3 = whi3 + 2 * WPREP3_N;
  float* xcl  = ws + OFF_XCL;  // channels-last x, dead h1t half (after conv2)
  float* savg = ws + OFF_PE;   // Savg over pe region (dead after attn_w)

  // weight prep (conv1 + conv2 + conv3)
  wprep_k<<<(WPREP_TOT + 255) / 256, 256, 0, stream>>>(
      w2e, w2t, w1e, w1t, w3e, w3t, whi, wlo, whi1, wlo1, whi3, wlo3);
  // conv1 (8 -> 64, relu) via MFMA -> bf16-RNE channels-last
  conv1_k<<<dim3(196, 1, 4), 256, 0, stream>>>(x, whi1, wlo1, b1e, h1e, b1t, h1t);
  // conv2 (64 -> 64, relu) via MFMA (bf16 input, 2-term) -> hi/lo for conv3
  conv2_mfma_k<<<dim3(392, 1, 4), 256, 0, stream>>>(h1e, h1t, whi, wlo, b2e, b2t,
                                                    h2ehi, h2elo, h2thi, h2tlo);
  // pack x channels-last into the now-dead h1t region
  xcl_k<<<(B_ * HW + 255) / 256, 256, 0, stream>>>(x, xcl);
  // conv3 (64 -> 8 / 64 -> 1) via MFMA, 8x16 tiles, branch+batch in z
  conv3_mfma_k<<<dim3(392, 1, 4), 256, 0, stream>>>(h2ehi, h2elo, h2thi, h2tlo,
                                                    whi3, wlo3, b3e, b3t, xe, ltm);
  // patches + norms + log-temp means fused
  prep_k<<<dim3(N_, B_), 256, 0, stream>>>(xe, ltm, pe, lt, sqv);
  // attention stage 1: weights
  attn_w_k<<<dim3((N_ + 3) / 4, B_), 256, 0, stream>>>(pe, lt, sqv, wkb);
  // precompute cell-averaged attention weights (pe region now dead)
  savg_k<<<(SAVG_N + 255) / 256, 256, 0, stream>>>(wkb, savg);
  // fused attn-PV + fold + passthrough (fast interior via Savg)
  foldpv_k<<<dim3(196, B_, 4), 256, 0, stream>>>(xcl, wkb, savg, out);
}

// Round 19
// 279.173 us; speedup vs baseline: 1.0203x; 1.0203x over previous
//
#include <hip/hip_runtime.h>
#include <math.h>

namespace {
constexpr int B_ = 2, CIN = 8, H_ = 224, W_ = 224;
constexpr int K_ = 7;
constexpr int F_ = 64, E_ = 8;
constexpr int N1 = 43, N2 = 43, N_ = N1 * N2;   // 1849
constexpr int M_ = 49;                           // candidates per query
constexpr int D_ = 800;                          // patch dim (C*P*P)
constexpr int HW = H_ * W_;

// workspace layout (floats).
constexpr size_t FHW = (size_t)B_ * F_ * HW;     // 6,422,528
constexpr size_t OFF_H1E = 0;                    // h1 bf16 channels-last (ushort)
constexpr size_t OFF_H1T = OFF_H1E + FHW;
constexpr size_t OFF_H2E = OFF_H1T + FHW;        // channels-last bf16 hi/lo
constexpr size_t OFF_H2T = OFF_H2E + FHW;
constexpr size_t OFF_WK  = 0;                    // B*N*343 = 1,268,414 < FHW
constexpr size_t OFF_XCL = OFF_H1T;              // x channels-last, dead h1t half
constexpr size_t OFF_XE  = OFF_H2T + FHW;
constexpr size_t OFF_LTM = OFF_XE + (size_t)B_ * E_ * HW;
constexpr size_t OFF_PE  = OFF_LTM + (size_t)B_ * HW;
constexpr size_t OFF_LT  = OFF_PE + (size_t)B_ * N_ * D_;
constexpr size_t OFF_SQ  = OFF_LT + (size_t)B_ * N_;
constexpr int WPREP_N = 294912;   // conv2: 2br * 2kcb * 9idx * 4wv * 64lane * 8j
constexpr int WPREP1_N = 12288;   // conv1: 2br * 3ky * 4wv * 64lane * 8j
constexpr int WPREP3_N = 9216;    // conv3 per-set: 2kcb * 9idx * 64lane * 8j
constexpr int WPREP_TOT = WPREP_N + WPREP1_N + 2 * WPREP3_N;
// Savg: per-2x2-query-block averaged wk, padded 392 per cell.
constexpr int SAVG_N = B_ * 42 * 42 * 392;       // 1,382,976 < pe region

__device__ __forceinline__ int clampi(int v, int lo, int hi) {
  return min(max(v, lo), hi);
}

// bijective XCD-chunk swizzle (m204).
__device__ __forceinline__ int xcd_swz(int x, int nwg) {
  int xcd = x & 7, idx = x >> 3;
  int q = nwg >> 3, r = nwg & 7;
  int base = (xcd < r) ? xcd * (q + 1) : r * (q + 1) + (xcd - r) * q;
  return base + idx;
}

// round-to-nearest-even fp32 -> bf16
__device__ __forceinline__ unsigned short bf16_rne(float v) {
  unsigned u = __float_as_uint(v);
  return (unsigned short)((u + 0x7FFFu + ((u >> 16) & 1u)) >> 16);
}

typedef __attribute__((ext_vector_type(8))) short short8;
typedef __attribute__((ext_vector_type(4))) float float4v;
typedef __attribute__((ext_vector_type(2))) float float2v;
typedef __attribute__((ext_vector_type(4))) unsigned short ushort4v;
} // namespace

// ---------------------------------------------------------------------------
// Weight prep: conv2, conv1, conv3(e), conv3(t) bf16 hi/lo splits (unchanged).
// ---------------------------------------------------------------------------
__global__ __launch_bounds__(256) void wprep_k(
    const float* __restrict__ w_e, const float* __restrict__ w_t,
    const float* __restrict__ w1e, const float* __restrict__ w1t,
    const float* __restrict__ w3e, const float* __restrict__ w3t,
    unsigned short* __restrict__ whi, unsigned short* __restrict__ wlo,
    unsigned short* __restrict__ whi1, unsigned short* __restrict__ wlo1,
    unsigned short* __restrict__ whi3, unsigned short* __restrict__ wlo3) {
  int t = blockIdx.x * 256 + threadIdx.x;
  if (t >= WPREP_TOT) return;
  float v;
  unsigned short* dh;
  unsigned short* dl;
  int di;
  if (t < WPREP_N) {
    int j = t & 7;
    int lane = (t >> 3) & 63;
    int wv = (t >> 9) & 3;
    int t2 = t >> 11;
    int idx = t2 % 9;
    int t3 = t2 / 9;
    int kcb = t3 & 1;
    int br = t3 >> 1;
    const float* wgt = br ? w_t : w_e;
    int co = wv * 16 + (lane & 15);
    int ci = kcb * 32 + 8 * (lane >> 4) + j;
    v = wgt[((size_t)co * 64 + ci) * 9 + idx];
    dh = whi; dl = wlo; di = t;
  } else if (t < WPREP_N + WPREP1_N) {
    int t1 = t - WPREP_N;
    int j = t1 & 7;
    int lane = (t1 >> 3) & 63;
    int wv = (t1 >> 9) & 3;
    int t2 = t1 >> 11;
    int ky = t2 % 3;
    int br = t2 / 3;
    const float* wgt = br ? w1t : w1e;
    int co = wv * 16 + (lane & 15);
    int kx = lane >> 4;
    int ci = j;
    v = (kx < 3) ? wgt[(((size_t)co * 8 + ci) * 3 + ky) * 3 + kx] : 0.f;
    dh = whi1; dl = wlo1; di = t1;
  } else {
    int t3v = t - WPREP_N - WPREP1_N;          // [0, 2*9216)
    int set = t3v / WPREP3_N;                   // 0 = e, 1 = t
    int rem = t3v - set * WPREP3_N;
    int j = rem & 7;
    int lane = (rem >> 3) & 63;
    int t2 = rem >> 9;                          // 0..17
    int idx = t2 % 9;
    int kcb = t2 / 9;
    int co = lane & 15;
    int ci = kcb * 32 + 8 * (lane >> 4) + j;
    if (set == 0)
      v = (co < 8) ? w3e[((size_t)co * 64 + ci) * 9 + idx] : 0.f;
    else
      v = (co == 0) ? w3t[(size_t)ci * 9 + idx] : 0.f;
    dh = whi3; dl = wlo3; di = t3v;
  }
  unsigned u = __float_as_uint(v);
  unsigned short hi = (unsigned short)(u >> 16);
  float rem = v - __uint_as_float(u & 0xffff0000u);
  unsigned short lo = (unsigned short)(__float_as_uint(rem) >> 16);
  dh[di] = hi;
  dl[di] = lo;
}

// ---------------------------------------------------------------------------
// conv1 (8->64, relu) via MFMA bf16 3-term hi/lo split -> bf16-RNE
// channels-last output (unchanged from R23).
// ---------------------------------------------------------------------------
__global__ __launch_bounds__(256) void conv1_k(
    const float* __restrict__ x,
    const unsigned short* __restrict__ whi1, const unsigned short* __restrict__ wlo1,
    const float* __restrict__ b_e, unsigned short* __restrict__ o_e,
    const float* __restrict__ b_t, unsigned short* __restrict__ o_t) {
  const int tile = blockIdx.x;
  const int b = blockIdx.z & 1;
  const int br = blockIdx.z >> 1;
  const float* bias = br ? b_t : b_e;
  unsigned short* out = br ? o_t : o_e;

  const int th0 = (tile / 14) * 16, tw0 = (tile % 14) * 16;
  const int tid = threadIdx.x;
  const int wv = tid >> 6, lane = tid & 63;
  const int q = lane >> 4, n = lane & 15;

  __shared__ unsigned short sT[342 * 20];   // 18 rows x 19 cols x (8hi+8lo)

  const float* xB = x + (size_t)b * CIN * HW;
#pragma unroll
  for (int it = 0; it < 2; ++it) {
    int s = tid + 256 * it;
    if (s < 342) {
      int lr = s / 19, lc = s - lr * 19;
      int gh = th0 + lr - 1, gw = tw0 + lc - 1;
      short8 h8, l8;
#pragma unroll
      for (int ci = 0; ci < 8; ++ci) { h8[ci] = 0; l8[ci] = 0; }
      if (lc < 18 && gh >= 0 && gh < H_ && gw >= 0 && gw < W_) {
        const float* xp = xB + (size_t)gh * W_ + gw;
#pragma unroll
        for (int ci = 0; ci < 8; ++ci) {
          float v = xp[(size_t)ci * HW];
          unsigned u = __float_as_uint(v);
          float rem = v - __uint_as_float(u & 0xffff0000u);
          h8[ci] = (short)(u >> 16);
          l8[ci] = (short)(__float_as_uint(rem) >> 16);
        }
      }
      *(short8*)&sT[s * 20] = h8;
      *(short8*)&sT[s * 20 + 8] = l8;
    }
  }

  const short8* wh8 = (const short8*)whi1;
  const short8* wl8 = (const short8*)wlo1;
  short8 Ah[3], Al[3];
#pragma unroll
  for (int ky = 0; ky < 3; ++ky) {
    int ab = ((br * 3 + ky) * 4 + wv) * 64 + lane;
    Ah[ky] = wh8[ab];
    Al[ky] = wl8[ab];
  }

  float4v acc[16];
#pragma unroll
  for (int pr = 0; pr < 16; ++pr) acc[pr] = (float4v)0.f;

  __syncthreads();

#pragma unroll
  for (int r = 0; r < 18; ++r) {
    const unsigned short* p = &sT[(r * 19 + n + q) * 20];
    short8 Bh = *(const short8*)p;
    short8 Bl = *(const short8*)(p + 8);
#pragma unroll
    for (int ky = 0; ky < 3; ++ky) {
      const int pr = r - ky;
      if (pr >= 0 && pr < 16) {
        acc[pr] = __builtin_amdgcn_mfma_f32_16x16x32_bf16(Ah[ky], Bh, acc[pr], 0, 0, 0);
        acc[pr] = __builtin_amdgcn_mfma_f32_16x16x32_bf16(Al[ky], Bh, acc[pr], 0, 0, 0);
        acc[pr] = __builtin_amdgcn_mfma_f32_16x16x32_bf16(Ah[ky], Bl, acc[pr], 0, 0, 0);
      }
    }
  }

  float4v bv = *(const float4v*)&bias[wv * 16 + 4 * q];
#pragma unroll
  for (int pr = 0; pr < 16; ++pr) {
    ushort4v hv;
#pragma unroll
    for (int r = 0; r < 4; ++r)
      hv[r] = bf16_rne(fmaxf(acc[pr][r] + bv[r], 0.f));
    *(ushort4v*)&out[(((size_t)b * H_ + th0 + pr) * W_ + tw0 + n) * 64 + wv * 16 + 4 * q] = hv;
  }
}

// ---------------------------------------------------------------------------
// conv2 (64->64, relu) via MFMA, bf16 input 2-term (unchanged from R23).
// ---------------------------------------------------------------------------
__global__ __launch_bounds__(256) void conv2_mfma_k(
    const unsigned short* __restrict__ in_e, const unsigned short* __restrict__ in_t,
    const unsigned short* __restrict__ whi, const unsigned short* __restrict__ wlo,
    const float* __restrict__ b_e, const float* __restrict__ b_t,
    unsigned short* __restrict__ ehi, unsigned short* __restrict__ elo,
    unsigned short* __restrict__ thi, unsigned short* __restrict__ tlo) {
  constexpr int NLD = 12;                       // ceil(2880/256)
  const int tile = blockIdx.x;                  // 28 x 14
  const int b = blockIdx.z & 1;
  const int br = blockIdx.z >> 1;
  const unsigned short* in = br ? in_t : in_e;
  const float* bias = br ? b_t : b_e;
  unsigned short* ohi = br ? thi : ehi;
  unsigned short* olo = br ? tlo : elo;

  const int th0 = (tile / 14) * 8, tw0 = (tile % 14) * 16;
  const int tid = threadIdx.x;
  const int wv = tid >> 6, lane = tid & 63;
  const int q = lane >> 4, n = lane & 15;

  __shared__ unsigned short sT[2 * 128 * 68];
  unsigned* sT32 = (unsigned*)sT;

  float4v acc[8];
#pragma unroll
  for (int pr = 0; pr < 8; ++pr) acc[pr] = (float4v)0.f;

  const unsigned short* inB = in + (size_t)b * HW * 64;
  const short8* whi8 = (const short8*)whi;
  const short8* wlo8 = (const short8*)wlo;

  int po[NLD];
  unsigned okm = 0;
#pragma unroll
  for (int j = 0; j < NLD; ++j) {
    int s = tid + 256 * j;
    int sp = s >> 4, cp = s & 15;
    int lr = sp / 18, lc = sp - lr * 18;
    int gh = th0 + lr - 1, gw = tw0 + lc - 1;
    bool ok = (s < 2880) && gh >= 0 && gh < H_ && gw >= 0 && gw < W_;
    po[j] = ok ? (gh * W_ + gw) * 64 + 2 * cp : 0;   // ushort units
    if (ok) okm |= (1u << j);
  }

  for (int kcb = 0; kcb < 2; ++kcb) {
    unsigned stg[NLD];
#pragma unroll
    for (int j = 0; j < NLD; ++j)
      stg[j] = *(const unsigned*)&inB[(size_t)po[j] + kcb * 32];

    __syncthreads();
#pragma unroll
    for (int j = 0; j < NLD; ++j) {
      int s = tid + 256 * j;
      if (s < 2880) {
        int sp = s >> 4, cp = s & 15;
        sT32[sp * 18 + cp] = ((okm >> j) & 1) ? stg[j] : 0u;
      }
    }
    __syncthreads();

    short8 Ah[9], Al[9];
    const int abase = (((br * 2 + kcb) * 9) * 4 + wv) * 64 + lane;
#pragma unroll
    for (int idx = 0; idx < 9; ++idx) {
      Ah[idx] = whi8[abase + idx * 256];
      Al[idx] = wlo8[abase + idx * 256];
    }

#pragma unroll
    for (int r = 0; r < 10; ++r) {
      short8 Bh[3];
#pragma unroll
      for (int kx = 0; kx < 3; ++kx)
        Bh[kx] = *(const short8*)&sT[(r * 18 + n + kx) * 36 + 8 * q];
#pragma unroll
      for (int ky = 0; ky < 3; ++ky) {
        const int pr = r - ky;
        if (pr >= 0 && pr < 8) {
#pragma unroll
          for (int kx = 0; kx < 3; ++kx) {
            const int idx = ky * 3 + kx;
            acc[pr] = __builtin_amdgcn_mfma_f32_16x16x32_bf16(Ah[idx], Bh[kx], acc[pr], 0, 0, 0);
            acc[pr] = __builtin_amdgcn_mfma_f32_16x16x32_bf16(Al[idx], Bh[kx], acc[pr], 0, 0, 0);
          }
        }
      }
    }
  }

  // ---- epilogue: bias+relu -> hi/lo, LDS transpose, dense stores ----
  float4v bv = *(const float4v*)&bias[wv * 16 + 4 * q];
  unsigned short* sHi = (unsigned short*)sT;     // [128][68]
  unsigned short* sLo = sHi + 128 * 68;
  __syncthreads();                               // all sT MFMA reads done
#pragma unroll
  for (int pr = 0; pr < 8; ++pr) {
    int px = pr * 16 + n;
    ushort4v hv, lv;
#pragma unroll
    for (int r = 0; r < 4; ++r) {
      float v = fmaxf(acc[pr][r] + bv[r], 0.f);
      unsigned u = __float_as_uint(v);
      float rem = v - __uint_as_float(u & 0xffff0000u);
      hv[r] = (unsigned short)(u >> 16);
      lv[r] = (unsigned short)(__float_as_uint(rem) >> 16);
    }
    *(ushort4v*)&sHi[px * 68 + wv * 16 + 4 * q] = hv;
    *(ushort4v*)&sLo[px * 68 + wv * 16 + 4 * q] = lv;
  }
  __syncthreads();
#pragma unroll
  for (int i = 0; i < 4; ++i) {
    int f = tid + 256 * i;
    int px = f >> 3, c8 = f & 7;
    int h = th0 + (px >> 4), w = tw0 + (px & 15);
    size_t o = ((size_t)(b * H_ + h) * W_ + w) * 64 + c8 * 8;
    *(short8*)&ohi[o] = *(const short8*)&sHi[px * 68 + c8 * 8];
    *(short8*)&olo[o] = *(const short8*)&sLo[px * 68 + c8 * 8];
  }
}

// ---------------------------------------------------------------------------
// conv3 via MFMA — R14 form (unchanged).
// ---------------------------------------------------------------------------
__global__ __launch_bounds__(256) void conv3_mfma_k(
    const unsigned short* __restrict__ h2ehi, const unsigned short* __restrict__ h2elo,
    const unsigned short* __restrict__ h2thi, const unsigned short* __restrict__ h2tlo,
    const unsigned short* __restrict__ whi3, const unsigned short* __restrict__ wlo3,
    const float* __restrict__ b3e, const float* __restrict__ b3t,
    float* __restrict__ xe, float* __restrict__ ltm) {
  constexpr int NLD = 12;                       // ceil(2880/256)
  const int tile = blockIdx.x;                  // 28 x 14
  const int b = blockIdx.z & 1;
  const int br = blockIdx.z >> 1;
  const unsigned short* ihi = (br ? h2thi : h2ehi) + (size_t)b * HW * 64;
  const unsigned short* ilo = (br ? h2tlo : h2elo) + (size_t)b * HW * 64;

  const int th0 = (tile / 14) * 8, tw0 = (tile % 14) * 16;
  const int tid = threadIdx.x;
  const int wv = tid >> 6, lane = tid & 63;
  const int q = lane >> 4, n = lane & 15;

  __shared__ unsigned short sT[180 * 72];       // 10x18 px, 25920 B
  unsigned* sT32 = (unsigned*)sT;

  int po[NLD];
  unsigned okm = 0;
#pragma unroll
  for (int j = 0; j < NLD; ++j) {
    int s = tid + 256 * j;
    int sp = s >> 4, cp = s & 15;
    int lr = sp / 18, lc = sp - lr * 18;
    int gh = th0 + lr - 1, gw = tw0 + lc - 1;
    bool ok = (s < 2880) && gh >= 0 && gh < H_ && gw >= 0 && gw < W_;
    po[j] = ok ? (gh * W_ + gw) * 64 + 2 * cp : 0;
    if (ok) okm |= (1u << j);
  }

  const short8* wh8 = (const short8*)whi3;
  const short8* wl8 = (const short8*)wlo3;
  const int brBase = br * 1152;                 // set stride in short8 units

  float4v acc[2];
  acc[0] = (float4v)0.f;
  acc[1] = (float4v)0.f;

  for (int kcb = 0; kcb < 2; ++kcb) {
    unsigned sgh[NLD], sgl[NLD];
#pragma unroll
    for (int j = 0; j < NLD; ++j) {
      sgh[j] = *(const unsigned*)&ihi[(size_t)po[j] + kcb * 32];
      sgl[j] = *(const unsigned*)&ilo[(size_t)po[j] + kcb * 32];
    }
    __syncthreads();
#pragma unroll
    for (int j = 0; j < NLD; ++j) {
      int s = tid + 256 * j;
      if (s < 2880) {
        int sp = s >> 4, cp = s & 15;
        bool ok = (okm >> j) & 1;
        sT32[sp * 36 + cp] = ok ? sgh[j] : 0u;
        sT32[sp * 36 + 16 + cp] = ok ? sgl[j] : 0u;
      }
    }
    __syncthreads();

    short8 Ah[9], Al[9];
#pragma unroll
    for (int idx = 0; idx < 9; ++idx) {
      int fe = brBase + (kcb * 9 + idx) * 64 + lane;
      Ah[idx] = wh8[fe];
      Al[idx] = wl8[fe];
    }

#pragma unroll
    for (int r = 0; r < 4; ++r) {
      const int rr = 2 * wv + r;
      short8 Bh[3], Bl[3];
#pragma unroll
      for (int kx = 0; kx < 3; ++kx) {
        const unsigned short* p = &sT[(rr * 18 + n + kx) * 72 + 8 * q];
        Bh[kx] = *(const short8*)p;
        Bl[kx] = *(const short8*)(p + 32);
      }
#pragma unroll
      for (int ky = 0; ky < 3; ++ky) {
        const int pl = r - ky;
        if (pl >= 0 && pl < 2) {
#pragma unroll
          for (int kx = 0; kx < 3; ++kx) {
            const int idx = ky * 3 + kx;
            acc[pl] = __builtin_amdgcn_mfma_f32_16x16x32_bf16(Ah[idx], Bh[kx], acc[pl], 0, 0, 0);
            acc[pl] = __builtin_amdgcn_mfma_f32_16x16x32_bf16(Al[idx], Bh[kx], acc[pl], 0, 0, 0);
            acc[pl] = __builtin_amdgcn_mfma_f32_16x16x32_bf16(Ah[idx], Bl[kx], acc[pl], 0, 0, 0);
          }
        }
      }
    }
  }

  if (br == 0) {
    if (q < 2) {                                // co = 4q+r in [0,8)
      float4v bv = *(const float4v*)&b3e[4 * q];
#pragma unroll
      for (int pl = 0; pl < 2; ++pl) {
        int h = th0 + 2 * wv + pl;
#pragma unroll
        for (int r = 0; r < 4; ++r)
          xe[((size_t)(b * 8 + 4 * q + r) * H_ + h) * W_ + tw0 + n] = acc[pl][r] + bv[r];
      }
    }
  } else {
    if (q == 0) {                               // co 0 = log_temp
      float bt = b3t[0];
#pragma unroll
      for (int pl = 0; pl < 2; ++pl) {
        int h = th0 + 2 * wv + pl;
        ltm[(size_t)b * HW + h * W_ + tw0 + n] = acc[pl][0] + bt;
      }
    }
  }
}

// ---------------------------------------------------------------------------
// xcl: pack x (NCHW) to channels-last [b][pix][8] (dead h1t region).
// ---------------------------------------------------------------------------
__global__ __launch_bounds__(256) void xcl_k(const float* __restrict__ x,
                                             float* __restrict__ xcl) {
  int i = blockIdx.x * 256 + threadIdx.x;
  if (i >= B_ * HW) return;
  int b = i / HW, pix = i % HW;
  const float* xp = x + (size_t)b * CIN * HW + pix;
  float4v v0, v1;
#pragma unroll
  for (int c = 0; c < 4; ++c) v0[c] = xp[(size_t)c * HW];
#pragma unroll
  for (int c = 0; c < 4; ++c) v1[c] = xp[(size_t)(4 + c) * HW];
  *(float4v*)&xcl[(size_t)i * 8] = v0;
  *(float4v*)&xcl[(size_t)i * 8 + 4] = v1;
}

// ---------------------------------------------------------------------------
// prep: write pe row (from xe), reduce sq and lt (unchanged).
// ---------------------------------------------------------------------------
__global__ __launch_bounds__(256) void prep_k(const float* __restrict__ xe,
                                              const float* __restrict__ ltm,
                                              float* __restrict__ pe,
                                              float* __restrict__ lt,
                                              float* __restrict__ sq) {
  const int n = blockIdx.x, b = blockIdx.y;
  const int tid = threadIdx.x;
  const int wv = tid >> 6, lane = tid & 63;
  const int q1 = n / N2, q2 = n % N2;
  const int r0 = q1 * 5, c0 = q2 * 5;

  float s = 0.f;
  float* peR = pe + ((size_t)b * N_ + n) * D_;
#pragma unroll
  for (int j = 0; j < 4; ++j) {
    int d = tid + 256 * j;
    if (d < D_) {
      int c = d / 100;
      int rr = (d / 10) % 10;
      int cc = d % 10;
      size_t si = ((size_t)(b * 8 + c) * H_ + r0 + rr) * W_ + c0 + cc;
      float ve = xe[si];
      peR[d] = ve;
      s += ve * ve;
    }
  }
  float t = 0.f;
  if (tid < 100) t = ltm[(size_t)b * HW + (r0 + tid / 10) * W_ + c0 + tid % 10];

#pragma unroll
  for (int off = 32; off > 0; off >>= 1) {
    s += __shfl_xor(s, off);
    t += __shfl_xor(t, off);
  }
  __shared__ float rs[4], rt[4];
  if (lane == 0) { rs[wv] = s; rt[wv] = t; }
  __syncthreads();
  if (tid == 0) {
    sq[b * N_ + n] = rs[0] + rs[1] + rs[2] + rs[3];
    lt[b * N_ + n] = (rt[0] + rt[1] + rt[2] + rt[3]) * 0.01f;
  }
}

// ---------------------------------------------------------------------------
// attn stage 1 (unchanged).
// ---------------------------------------------------------------------------
__global__ __launch_bounds__(256) void attn_w_k(const float* __restrict__ pe,
                                                const float* __restrict__ lt,
                                                const float* __restrict__ sq,
                                                float* __restrict__ wk) {
  const int wv = threadIdx.x >> 6, lane = threadIdx.x & 63;
  const int ng = xcd_swz(blockIdx.x, (N_ + 3) / 4);
  const int n = ng * 4 + wv;
  if (n >= N_) return;
  const int b = blockIdx.y;
  const int q1 = n / N2, q2 = n % N2;

  const float* peB = pe + (size_t)b * N_ * D_;
  const float* qrow = peB + (size_t)n * D_;
  float q[13];
#pragma unroll
  for (int t = 0; t < 13; ++t) {
    int s = t * 64 + lane;
    q[t] = (s < D_) ? qrow[s] : 0.f;
  }

  const float sqn = sq[b * N_ + n];
  const float itemp = expf(-lt[b * N_ + n]);
  float gm = -INFINITY;

  for (int o1 = 0; o1 < 7; ++o1) {
    int c1 = clampi(q1 + o1 - 3, 0, N1 - 1);
    const float* rowb = peB + (size_t)(c1 * N2) * D_;
#pragma unroll
    for (int o2 = 0; o2 < 7; ++o2) {
      int c2 = clampi(q2 + o2 - 3, 0, N2 - 1);
      int cn = c1 * N2 + c2;
      const float* crow = rowb + (size_t)c2 * D_;
      float a = 0.f;
#pragma unroll
      for (int t = 0; t < 13; ++t) {
        float v;
        if (t < 12) v = crow[t * 64 + lane];
        else v = (lane < 32) ? crow[768 + lane] : 0.f;
        a += q[t] * v;
      }
#pragma unroll
      for (int off = 32; off > 0; off >>= 1) a += __shfl_xor(a, off);
      float Dv = -(sqn + sq[b * N_ + cn] - 2.f * a);
      float lg = (cn == n) ? -1e9f : Dv * itemp;
      const int m = o1 * 7 + o2;
      gm = (lane == m) ? lg : gm;
    }
  }

  float cur = (lane < M_) ? gm : -INFINITY;
  float* wrow = wk + (size_t)(b * N_ + n) * (M_ * K_);
#pragma unroll
  for (int k = 0; k < K_; ++k) {
    float mx = cur;
#pragma unroll
    for (int off = 32; off > 0; off >>= 1) mx = fmaxf(mx, __shfl_xor(mx, off));
    float e = (lane < M_) ? expf(cur - mx) : 0.f;
    float ssum = e;
#pragma unroll
    for (int off = 32; off > 0; off >>= 1) ssum += __shfl_xor(ssum, off);
    float w = e / ssum;
    if (lane < M_) wrow[lane * K_ + k] = w;
    cur += log1pf(-fminf(w, 1.f - 1e-6f));
  }
}

// ---------------------------------------------------------------------------
// savg: per-2x2-query-block averaged wk, padded 8/m (validated in R24).
// ---------------------------------------------------------------------------
__global__ __launch_bounds__(256) void savg_k(const float* __restrict__ wk,
                                              float* __restrict__ savg) {
  int i = blockIdx.x * 256 + threadIdx.x;
  if (i >= SAVG_N) return;
  int r = i % 392;
  int t = i / 392;
  int cl2 = t % 42;
  int t2 = t / 42;
  int cl1 = t2 % 42;
  int b = t2 / 42;
  int m = r >> 3, k = r & 7;
  float v = 0.f;
  if (k < 7) {
    size_t base = (size_t)(b * N_ + cl1 * N2 + cl2) * (M_ * K_) + m * 7 + k;
    v = 0.25f * (wk[base] + wk[base + M_ * K_] +
                 wk[base + (size_t)N2 * (M_ * K_)] +
                 wk[base + (size_t)(N2 + 1) * (M_ * K_)]);
  }
  savg[i] = v;
}

// ---------------------------------------------------------------------------
// foldpv R25 (resubmit): z=2 (4 channels/block, proven R23 structure) +
// Savg-based fast staging (1 load/value vs 4 loads + 3 adds). Numerics
// identical to R23/R24 (savg reproduces the 0.25f*(a+b+c+d) order).
// ---------------------------------------------------------------------------
__global__ __launch_bounds__(256) void foldpv_k(const float* __restrict__ xcl,
                                                const float* __restrict__ wk,
                                                const float* __restrict__ savg,
                                                float* __restrict__ out) {
  const int tile = xcd_swz(blockIdx.x, 196);
  const int b = blockIdx.y;
  const int c0 = blockIdx.z * 4;               // channels c0..c0+3
  const int t1 = tile / 14, t2 = tile % 14;
  const int ty0 = t1 * 16, tx0 = t2 * 16;
  const int tid = threadIdx.x;
  const int h = ty0 + (tid >> 4), w = tx0 + (tid & 15);
  const bool fast = (t1 >= 2 && t1 <= 11 && t2 >= 2 && t2 <= 11);

  __shared__ float smem[25 * 392];             // 39.2 KB (fast uses 16*392)

  const float* xclB = xcl + (size_t)b * HW * 8;
  const int pix = h * W_ + w;
  float* outB = out + (size_t)b * 64 * HW + pix;

  // x passthrough (4 channels per z)
  {
    float4v pv = *(const float4v*)&xclB[(size_t)pix * 8 + c0];
#pragma unroll
    for (int c = 0; c < 4; ++c) outB[(size_t)(c0 + c) * HW] = pv[c];
  }

  float acc[4][7];
#pragma unroll
  for (int c = 0; c < 4; ++c)
#pragma unroll
    for (int k = 0; k < 7; ++k) acc[c][k] = 0.f;

  if (fast) {
    const int cl1_0 = (ty0 - 5) / 5, cl2_0 = (tx0 - 5) / 5;
    const float* sb = savg + (size_t)b * 42 * 42 * 392;
    for (int s = tid; s < 16 * 392; s += 256) {
      int cell = s / 392, r = s - cell * 392;
      int q1c = cl1_0 + (cell >> 2), q2c = cl2_0 + (cell & 3);
      smem[s] = sb[((size_t)q1c * 42 + q2c) * 392 + r];
    }
    __syncthreads();

    const int cl1 = (h - 5) / 5 - cl1_0, cl2 = (w - 5) / 5 - cl2_0;
    const float* sSp = smem + (cl1 * 4 + cl2) * 392;
    int roff[7], coff[7];
#pragma unroll
    for (int o = 0; o < 7; ++o) {
      roff[o] = (h + 5 * (o - 3)) * W_;
      coff[o] = w + 5 * (o - 3);
    }
#pragma unroll
    for (int o1 = 0; o1 < 7; ++o1) {
#pragma unroll
      for (int o2 = 0; o2 < 7; ++o2) {
        float4v xv = *(const float4v*)&xclB[((size_t)(roff[o1] + coff[o2])) * 8 + c0];
        const float* sp = sSp + (o1 * 7 + o2) * 8;
        float4v w4 = *(const float4v*)sp;
        float2v w2 = *(const float2v*)(sp + 4);
        float w6 = sp[6];
#pragma unroll
        for (int c = 0; c < 4; ++c) {
          acc[c][0] += w4[0] * xv[c];
          acc[c][1] += w4[1] * xv[c];
          acc[c][2] += w4[2] * xv[c];
          acc[c][3] += w4[3] * xv[c];
          acc[c][4] += w2[0] * xv[c];
          acc[c][5] += w2[1] * xv[c];
          acc[c][6] += w6 * xv[c];
        }
      }
    }
#pragma unroll
    for (int k = 0; k < 7; ++k)
#pragma unroll
      for (int c = 0; c < 4; ++c)
        outB[(size_t)(8 + k * 8 + c0 + c) * HW] = acc[c][k];
    return;
  }

  // ---- slow path ----
  const int q1lo_t = max(0, (ty0 - 5) / 5), q1hi_t = min(N1 - 1, (ty0 + 15) / 5);
  const int q2lo_t = max(0, (tx0 - 5) / 5), q2hi_t = min(N2 - 1, (tx0 + 15) / 5);
  const int nq1 = q1hi_t - q1lo_t + 1, nq2 = q2hi_t - q2lo_t + 1;

  {
    const int tot = nq1 * nq2 * 392;
    for (int s = tid; s < tot; s += 256) {
      int lq = s / 392, r = s - lq * 392;
      int m = r >> 3, k = r & 7;
      int n = (q1lo_t + lq / nq2) * N2 + (q2lo_t + lq % nq2);
      smem[s] = (k < 7) ? wk[(size_t)(b * N_ + n) * (M_ * K_) + m * 7 + k] : 0.f;
    }
  }
  __syncthreads();

  const int q1lo = max(0, (h - 5) / 5), q1hi = min(N1 - 1, h / 5);
  const int q2lo = max(0, (w - 5) / 5), q2hi = min(N2 - 1, w / 5);

  int cnt = 0;
  for (int q1 = q1lo; q1 <= q1hi; ++q1) {
    const int ib = h - 5 * q1;
    const int lq1 = q1 - q1lo_t;
    for (int q2 = q2lo; q2 <= q2hi; ++q2) {
      ++cnt;
      const int jb = w - 5 * q2;
      const float* wq = smem + (lq1 * nq2 + (q2 - q2lo_t)) * 392;
#pragma unroll
      for (int o1 = 0; o1 < 7; ++o1) {
        const int c1 = clampi(q1 + o1 - 3, 0, N1 - 1);
        const int row = c1 * 5 + ib;
#pragma unroll
        for (int o2 = 0; o2 < 7; ++o2) {
          const int c2 = clampi(q2 + o2 - 3, 0, N2 - 1);
          const int col = c2 * 5 + jb;
          float4v xv = *(const float4v*)&xclB[((size_t)row * W_ + col) * 8 + c0];
          const float* wp = wq + (o1 * 7 + o2) * 8;
          float4v w4 = *(const float4v*)wp;
          float2v w2 = *(const float2v*)(wp + 4);
          float w6 = wp[6];
#pragma unroll
          for (int c = 0; c < 4; ++c) {
            acc[c][0] += w4[0] * xv[c];
            acc[c][1] += w4[1] * xv[c];
            acc[c][2] += w4[2] * xv[c];
            acc[c][3] += w4[3] * xv[c];
            acc[c][4] += w2[0] * xv[c];
            acc[c][5] += w2[1] * xv[c];
            acc[c][6] += w6 * xv[c];
          }
        }
      }
    }
  }

  const float inv = (cnt > 0) ? 1.f / (float)cnt : 0.f;  // cnt in {0,1,2,4}
#pragma unroll
  for (int k = 0; k < 7; ++k)
#pragma unroll
    for (int c = 0; c < 4; ++c)
      outB[(size_t)(8 + k * 8 + c0 + c) * HW] = acc[c][k] * inv;
}

extern "C" void kernel_launch(void* const* d_in, const int* in_sizes, int n_in,
                              void* d_out, int out_size, void* d_ws,
                              size_t ws_size, hipStream_t stream) {
  const float* x   = (const float*)d_in[0];
  const float* w1e = (const float*)d_in[1];
  const float* b1e = (const float*)d_in[2];
  const float* w2e = (const float*)d_in[3];
  const float* b2e = (const float*)d_in[4];
  const float* w3e = (const float*)d_in[5];
  const float* b3e = (const float*)d_in[6];
  const float* w1t = (const float*)d_in[7];
  const float* b1t = (const float*)d_in[8];
  const float* w2t = (const float*)d_in[9];
  const float* b2t = (const float*)d_in[10];
  const float* w3t = (const float*)d_in[11];
  const float* b3t = (const float*)d_in[12];

  float* ws  = (float*)d_ws;
  float* out = (float*)d_out;

  unsigned short* h1e = (unsigned short*)(ws + OFF_H1E);   // bf16 channels-last
  unsigned short* h1t = (unsigned short*)(ws + OFF_H1T);
  unsigned short* h2ehi = (unsigned short*)(ws + OFF_H2E);   // channels-last hi/lo
  unsigned short* h2elo = h2ehi + (size_t)B_ * HW * 64;
  unsigned short* h2thi = (unsigned short*)(ws + OFF_H2T);
  unsigned short* h2tlo = h2thi + (size_t)B_ * HW * 64;
  float* wkb = ws + OFF_WK;
  float* xe  = ws + OFF_XE;
  float* ltm = ws + OFF_LTM;
  float* pe  = ws + OFF_PE;
  float* lt  = ws + OFF_LT;
  float* sqv = ws + OFF_SQ;
  unsigned short* whi  = (unsigned short*)(ws + OFF_XE);  // consumed before xe written
  unsigned short* wlo  = whi + WPREP_N;
  unsigned short* whi1 = wlo + WPREP_N;
  unsigned short* wlo1 = whi1 + WPREP1_N;
  unsigned short* whi3 = (unsigned short*)(ws + OFF_PE);  // consumed before pe written
  unsigned short* wlo3 = whi3 + 2 * WPREP3_N;
  float* xcl  = ws + OFF_XCL;  // channels-last x, dead h1t half (after conv2)
  float* savg = ws + OFF_PE;   // Savg over pe region (dead after attn_w)

  // weight prep (conv1 + conv2 + conv3)
  wprep_k<<<(WPREP_TOT + 255) / 256, 256, 0, stream>>>(
      w2e, w2t, w1e, w1t, w3e, w3t, whi, wlo, whi1, wlo1, whi3, wlo3);
  // conv1 (8 -> 64, relu) via MFMA -> bf16-RNE channels-last
  conv1_k<<<dim3(196, 1, 4), 256, 0, stream>>>(x, whi1, wlo1, b1e, h1e, b1t, h1t);
  // conv2 (64 -> 64, relu) via MFMA (bf16 input, 2-term) -> hi/lo for conv3
  conv2_mfma_k<<<dim3(392, 1, 4), 256, 0, stream>>>(h1e, h1t, whi, wlo, b2e, b2t,
                                                    h2ehi, h2elo, h2thi, h2tlo);
  // pack x channels-last into the now-dead h1t region
  xcl_k<<<(B_ * HW + 255) / 256, 256, 0, stream>>>(x, xcl);
  // conv3 (64 -> 8 / 64 -> 1) via MFMA, 8x16 tiles, branch+batch in z
  conv3_mfma_k<<<dim3(392, 1, 4), 256, 0, stream>>>(h2ehi, h2elo, h2thi, h2tlo,
                                                    whi3, wlo3, b3e, b3t, xe, ltm);
  // patches + norms + log-temp means fused
  prep_k<<<dim3(N_, B_), 256, 0, stream>>>(xe, ltm, pe, lt, sqv);
  // attention stage 1: weights
  attn_w_k<<<dim3((N_ + 3) / 4, B_), 256, 0, stream>>>(pe, lt, sqv, wkb);
  // precompute cell-averaged attention weights (pe region now dead)
  savg_k<<<(SAVG_N + 255) / 256, 256, 0, stream>>>(wkb, savg);
  // fused attn-PV + fold + passthrough (fast interior via Savg, z=2)
  foldpv_k<<<dim3(196, B_, 2), 256, 0, stream>>>(xcl, wkb, savg, out);
}

// Round 20
// 271.230 us; speedup vs baseline: 1.0502x; 1.0293x over previous
//
#include <hip/hip_runtime.h>
#include <math.h>

namespace {
constexpr int B_ = 2, CIN = 8, H_ = 224, W_ = 224;
constexpr int K_ = 7;
constexpr int F_ = 64, E_ = 8;
constexpr int N1 = 43, N2 = 43, N_ = N1 * N2;   // 1849
constexpr int M_ = 49;                           // candidates per query
constexpr int D_ = 800;                          // patch dim (C*P*P)
constexpr int HW = H_ * W_;

// workspace layout (floats).
constexpr size_t FHW = (size_t)B_ * F_ * HW;     // 6,422,528
constexpr size_t OFF_H1E = 0;                    // h1 bf16 channels-last (ushort)
constexpr size_t OFF_H1T = OFF_H1E + FHW;
constexpr size_t OFF_H2E = OFF_H1T + FHW;        // channels-last bf16 hi/lo
constexpr size_t OFF_H2T = OFF_H2E + FHW;
constexpr size_t OFF_WK  = 0;                    // B*N*343 = 1,268,414 < FHW
constexpr size_t OFF_XCL = OFF_H1T;              // x channels-last, dead h1t half
constexpr size_t OFF_XE  = OFF_H2T + FHW;
constexpr size_t OFF_LTM = OFF_XE + (size_t)B_ * E_ * HW;
constexpr size_t OFF_PE  = OFF_LTM + (size_t)B_ * HW;
constexpr size_t OFF_LT  = OFF_PE + (size_t)B_ * N_ * D_;
constexpr size_t OFF_SQ  = OFF_LT + (size_t)B_ * N_;
constexpr int WPREP_N = 294912;   // conv2: 2br * 2kcb * 9idx * 4wv * 64lane * 8j
constexpr int WPREP1_N = 12288;   // conv1: 2br * 3ky * 4wv * 64lane * 8j
constexpr int WPREP3_N = 9216;    // conv3 per-set: 2kcb * 9idx * 64lane * 8j
constexpr int WPREP_TOT = WPREP_N + WPREP1_N + 2 * WPREP3_N;

__device__ __forceinline__ int clampi(int v, int lo, int hi) {
  return min(max(v, lo), hi);
}

// bijective XCD-chunk swizzle (m204).
__device__ __forceinline__ int xcd_swz(int x, int nwg) {
  int xcd = x & 7, idx = x >> 3;
  int q = nwg >> 3, r = nwg & 7;
  int base = (xcd < r) ? xcd * (q + 1) : r * (q + 1) + (xcd - r) * q;
  return base + idx;
}

// round-to-nearest-even fp32 -> bf16
__device__ __forceinline__ unsigned short bf16_rne(float v) {
  unsigned u = __float_as_uint(v);
  return (unsigned short)((u + 0x7FFFu + ((u >> 16) & 1u)) >> 16);
}

typedef __attribute__((ext_vector_type(8))) short short8;
typedef __attribute__((ext_vector_type(4))) float float4v;
typedef __attribute__((ext_vector_type(2))) float float2v;
typedef __attribute__((ext_vector_type(4))) unsigned short ushort4v;
} // namespace

// ---------------------------------------------------------------------------
// Weight prep: conv2, conv1, conv3(e), conv3(t) bf16 hi/lo splits (unchanged).
// ---------------------------------------------------------------------------
__global__ __launch_bounds__(256) void wprep_k(
    const float* __restrict__ w_e, const float* __restrict__ w_t,
    const float* __restrict__ w1e, const float* __restrict__ w1t,
    const float* __restrict__ w3e, const float* __restrict__ w3t,
    unsigned short* __restrict__ whi, unsigned short* __restrict__ wlo,
    unsigned short* __restrict__ whi1, unsigned short* __restrict__ wlo1,
    unsigned short* __restrict__ whi3, unsigned short* __restrict__ wlo3) {
  int t = blockIdx.x * 256 + threadIdx.x;
  if (t >= WPREP_TOT) return;
  float v;
  unsigned short* dh;
  unsigned short* dl;
  int di;
  if (t < WPREP_N) {
    int j = t & 7;
    int lane = (t >> 3) & 63;
    int wv = (t >> 9) & 3;
    int t2 = t >> 11;
    int idx = t2 % 9;
    int t3 = t2 / 9;
    int kcb = t3 & 1;
    int br = t3 >> 1;
    const float* wgt = br ? w_t : w_e;
    int co = wv * 16 + (lane & 15);
    int ci = kcb * 32 + 8 * (lane >> 4) + j;
    v = wgt[((size_t)co * 64 + ci) * 9 + idx];
    dh = whi; dl = wlo; di = t;
  } else if (t < WPREP_N + WPREP1_N) {
    int t1 = t - WPREP_N;
    int j = t1 & 7;
    int lane = (t1 >> 3) & 63;
    int wv = (t1 >> 9) & 3;
    int t2 = t1 >> 11;
    int ky = t2 % 3;
    int br = t2 / 3;
    const float* wgt = br ? w1t : w1e;
    int co = wv * 16 + (lane & 15);
    int kx = lane >> 4;
    int ci = j;
    v = (kx < 3) ? wgt[(((size_t)co * 8 + ci) * 3 + ky) * 3 + kx] : 0.f;
    dh = whi1; dl = wlo1; di = t1;
  } else {
    int t3v = t - WPREP_N - WPREP1_N;          // [0, 2*9216)
    int set = t3v / WPREP3_N;                   // 0 = e, 1 = t
    int rem = t3v - set * WPREP3_N;
    int j = rem & 7;
    int lane = (rem >> 3) & 63;
    int t2 = rem >> 9;                          // 0..17
    int idx = t2 % 9;
    int kcb = t2 / 9;
    int co = lane & 15;
    int ci = kcb * 32 + 8 * (lane >> 4) + j;
    if (set == 0)
      v = (co < 8) ? w3e[((size_t)co * 64 + ci) * 9 + idx] : 0.f;
    else
      v = (co == 0) ? w3t[(size_t)ci * 9 + idx] : 0.f;
    dh = whi3; dl = wlo3; di = t3v;
  }
  unsigned u = __float_as_uint(v);
  unsigned short hi = (unsigned short)(u >> 16);
  float rem = v - __uint_as_float(u & 0xffff0000u);
  unsigned short lo = (unsigned short)(__float_as_uint(rem) >> 16);
  dh[di] = hi;
  dl[di] = lo;
}

// ---------------------------------------------------------------------------
// conv1 (8->64, relu) via MFMA bf16 3-term hi/lo split -> bf16-RNE
// channels-last output (unchanged from R23).
// ---------------------------------------------------------------------------
__global__ __launch_bounds__(256) void conv1_k(
    const float* __restrict__ x,
    const unsigned short* __restrict__ whi1, const unsigned short* __restrict__ wlo1,
    const float* __restrict__ b_e, unsigned short* __restrict__ o_e,
    const float* __restrict__ b_t, unsigned short* __restrict__ o_t) {
  const int tile = blockIdx.x;
  const int b = blockIdx.z & 1;
  const int br = blockIdx.z >> 1;
  const float* bias = br ? b_t : b_e;
  unsigned short* out = br ? o_t : o_e;

  const int th0 = (tile / 14) * 16, tw0 = (tile % 14) * 16;
  const int tid = threadIdx.x;
  const int wv = tid >> 6, lane = tid & 63;
  const int q = lane >> 4, n = lane & 15;

  __shared__ unsigned short sT[342 * 20];   // 18 rows x 19 cols x (8hi+8lo)

  const float* xB = x + (size_t)b * CIN * HW;
#pragma unroll
  for (int it = 0; it < 2; ++it) {
    int s = tid + 256 * it;
    if (s < 342) {
      int lr = s / 19, lc = s - lr * 19;
      int gh = th0 + lr - 1, gw = tw0 + lc - 1;
      short8 h8, l8;
#pragma unroll
      for (int ci = 0; ci < 8; ++ci) { h8[ci] = 0; l8[ci] = 0; }
      if (lc < 18 && gh >= 0 && gh < H_ && gw >= 0 && gw < W_) {
        const float* xp = xB + (size_t)gh * W_ + gw;
#pragma unroll
        for (int ci = 0; ci < 8; ++ci) {
          float v = xp[(size_t)ci * HW];
          unsigned u = __float_as_uint(v);
          float rem = v - __uint_as_float(u & 0xffff0000u);
          h8[ci] = (short)(u >> 16);
          l8[ci] = (short)(__float_as_uint(rem) >> 16);
        }
      }
      *(short8*)&sT[s * 20] = h8;
      *(short8*)&sT[s * 20 + 8] = l8;
    }
  }

  const short8* wh8 = (const short8*)whi1;
  const short8* wl8 = (const short8*)wlo1;
  short8 Ah[3], Al[3];
#pragma unroll
  for (int ky = 0; ky < 3; ++ky) {
    int ab = ((br * 3 + ky) * 4 + wv) * 64 + lane;
    Ah[ky] = wh8[ab];
    Al[ky] = wl8[ab];
  }

  float4v acc[16];
#pragma unroll
  for (int pr = 0; pr < 16; ++pr) acc[pr] = (float4v)0.f;

  __syncthreads();

#pragma unroll
  for (int r = 0; r < 18; ++r) {
    const unsigned short* p = &sT[(r * 19 + n + q) * 20];
    short8 Bh = *(const short8*)p;
    short8 Bl = *(const short8*)(p + 8);
#pragma unroll
    for (int ky = 0; ky < 3; ++ky) {
      const int pr = r - ky;
      if (pr >= 0 && pr < 16) {
        acc[pr] = __builtin_amdgcn_mfma_f32_16x16x32_bf16(Ah[ky], Bh, acc[pr], 0, 0, 0);
        acc[pr] = __builtin_amdgcn_mfma_f32_16x16x32_bf16(Al[ky], Bh, acc[pr], 0, 0, 0);
        acc[pr] = __builtin_amdgcn_mfma_f32_16x16x32_bf16(Ah[ky], Bl, acc[pr], 0, 0, 0);
      }
    }
  }

  float4v bv = *(const float4v*)&bias[wv * 16 + 4 * q];
#pragma unroll
  for (int pr = 0; pr < 16; ++pr) {
    ushort4v hv;
#pragma unroll
    for (int r = 0; r < 4; ++r)
      hv[r] = bf16_rne(fmaxf(acc[pr][r] + bv[r], 0.f));
    *(ushort4v*)&out[(((size_t)b * H_ + th0 + pr) * W_ + tw0 + n) * 64 + wv * 16 + 4 * q] = hv;
  }
}

// ---------------------------------------------------------------------------
// conv2 (64->64, relu) via MFMA, bf16 input 2-term (unchanged from R23).
// ---------------------------------------------------------------------------
__global__ __launch_bounds__(256) void conv2_mfma_k(
    const unsigned short* __restrict__ in_e, const unsigned short* __restrict__ in_t,
    const unsigned short* __restrict__ whi, const unsigned short* __restrict__ wlo,
    const float* __restrict__ b_e, const float* __restrict__ b_t,
    unsigned short* __restrict__ ehi, unsigned short* __restrict__ elo,
    unsigned short* __restrict__ thi, unsigned short* __restrict__ tlo) {
  constexpr int NLD = 12;                       // ceil(2880/256)
  const int tile = blockIdx.x;                  // 28 x 14
  const int b = blockIdx.z & 1;
  const int br = blockIdx.z >> 1;
  const unsigned short* in = br ? in_t : in_e;
  const float* bias = br ? b_t : b_e;
  unsigned short* ohi = br ? thi : ehi;
  unsigned short* olo = br ? tlo : elo;

  const int th0 = (tile / 14) * 8, tw0 = (tile % 14) * 16;
  const int tid = threadIdx.x;
  const int wv = tid >> 6, lane = tid & 63;
  const int q = lane >> 4, n = lane & 15;

  __shared__ unsigned short sT[2 * 128 * 68];
  unsigned* sT32 = (unsigned*)sT;

  float4v acc[8];
#pragma unroll
  for (int pr = 0; pr < 8; ++pr) acc[pr] = (float4v)0.f;

  const unsigned short* inB = in + (size_t)b * HW * 64;
  const short8* whi8 = (const short8*)whi;
  const short8* wlo8 = (const short8*)wlo;

  int po[NLD];
  unsigned okm = 0;
#pragma unroll
  for (int j = 0; j < NLD; ++j) {
    int s = tid + 256 * j;
    int sp = s >> 4, cp = s & 15;
    int lr = sp / 18, lc = sp - lr * 18;
    int gh = th0 + lr - 1, gw = tw0 + lc - 1;
    bool ok = (s < 2880) && gh >= 0 && gh < H_ && gw >= 0 && gw < W_;
    po[j] = ok ? (gh * W_ + gw) * 64 + 2 * cp : 0;   // ushort units
    if (ok) okm |= (1u << j);
  }

  for (int kcb = 0; kcb < 2; ++kcb) {
    unsigned stg[NLD];
#pragma unroll
    for (int j = 0; j < NLD; ++j)
      stg[j] = *(const unsigned*)&inB[(size_t)po[j] + kcb * 32];

    __syncthreads();
#pragma unroll
    for (int j = 0; j < NLD; ++j) {
      int s = tid + 256 * j;
      if (s < 2880) {
        int sp = s >> 4, cp = s & 15;
        sT32[sp * 18 + cp] = ((okm >> j) & 1) ? stg[j] : 0u;
      }
    }
    __syncthreads();

    short8 Ah[9], Al[9];
    const int abase = (((br * 2 + kcb) * 9) * 4 + wv) * 64 + lane;
#pragma unroll
    for (int idx = 0; idx < 9; ++idx) {
      Ah[idx] = whi8[abase + idx * 256];
      Al[idx] = wlo8[abase + idx * 256];
    }

#pragma unroll
    for (int r = 0; r < 10; ++r) {
      short8 Bh[3];
#pragma unroll
      for (int kx = 0; kx < 3; ++kx)
        Bh[kx] = *(const short8*)&sT[(r * 18 + n + kx) * 36 + 8 * q];
#pragma unroll
      for (int ky = 0; ky < 3; ++ky) {
        const int pr = r - ky;
        if (pr >= 0 && pr < 8) {
#pragma unroll
          for (int kx = 0; kx < 3; ++kx) {
            const int idx = ky * 3 + kx;
            acc[pr] = __builtin_amdgcn_mfma_f32_16x16x32_bf16(Ah[idx], Bh[kx], acc[pr], 0, 0, 0);
            acc[pr] = __builtin_amdgcn_mfma_f32_16x16x32_bf16(Al[idx], Bh[kx], acc[pr], 0, 0, 0);
          }
        }
      }
    }
  }

  // ---- epilogue: bias+relu -> hi/lo, LDS transpose, dense stores ----
  float4v bv = *(const float4v*)&bias[wv * 16 + 4 * q];
  unsigned short* sHi = (unsigned short*)sT;     // [128][68]
  unsigned short* sLo = sHi + 128 * 68;
  __syncthreads();                               // all sT MFMA reads done
#pragma unroll
  for (int pr = 0; pr < 8; ++pr) {
    int px = pr * 16 + n;
    ushort4v hv, lv;
#pragma unroll
    for (int r = 0; r < 4; ++r) {
      float v = fmaxf(acc[pr][r] + bv[r], 0.f);
      unsigned u = __float_as_uint(v);
      float rem = v - __uint_as_float(u & 0xffff0000u);
      hv[r] = (unsigned short)(u >> 16);
      lv[r] = (unsigned short)(__float_as_uint(rem) >> 16);
    }
    *(ushort4v*)&sHi[px * 68 + wv * 16 + 4 * q] = hv;
    *(ushort4v*)&sLo[px * 68 + wv * 16 + 4 * q] = lv;
  }
  __syncthreads();
#pragma unroll
  for (int i = 0; i < 4; ++i) {
    int f = tid + 256 * i;
    int px = f >> 3, c8 = f & 7;
    int h = th0 + (px >> 4), w = tw0 + (px & 15);
    size_t o = ((size_t)(b * H_ + h) * W_ + w) * 64 + c8 * 8;
    *(short8*)&ohi[o] = *(const short8*)&sHi[px * 68 + c8 * 8];
    *(short8*)&olo[o] = *(const short8*)&sLo[px * 68 + c8 * 8];
  }
}

// ---------------------------------------------------------------------------
// conv3 via MFMA — R14 form (unchanged).
// ---------------------------------------------------------------------------
__global__ __launch_bounds__(256) void conv3_mfma_k(
    const unsigned short* __restrict__ h2ehi, const unsigned short* __restrict__ h2elo,
    const unsigned short* __restrict__ h2thi, const unsigned short* __restrict__ h2tlo,
    const unsigned short* __restrict__ whi3, const unsigned short* __restrict__ wlo3,
    const float* __restrict__ b3e, const float* __restrict__ b3t,
    float* __restrict__ xe, float* __restrict__ ltm) {
  constexpr int NLD = 12;                       // ceil(2880/256)
  const int tile = blockIdx.x;                  // 28 x 14
  const int b = blockIdx.z & 1;
  const int br = blockIdx.z >> 1;
  const unsigned short* ihi = (br ? h2thi : h2ehi) + (size_t)b * HW * 64;
  const unsigned short* ilo = (br ? h2tlo : h2elo) + (size_t)b * HW * 64;

  const int th0 = (tile / 14) * 8, tw0 = (tile % 14) * 16;
  const int tid = threadIdx.x;
  const int wv = tid >> 6, lane = tid & 63;
  const int q = lane >> 4, n = lane & 15;

  __shared__ unsigned short sT[180 * 72];       // 10x18 px, 25920 B
  unsigned* sT32 = (unsigned*)sT;

  int po[NLD];
  unsigned okm = 0;
#pragma unroll
  for (int j = 0; j < NLD; ++j) {
    int s = tid + 256 * j;
    int sp = s >> 4, cp = s & 15;
    int lr = sp / 18, lc = sp - lr * 18;
    int gh = th0 + lr - 1, gw = tw0 + lc - 1;
    bool ok = (s < 2880) && gh >= 0 && gh < H_ && gw >= 0 && gw < W_;
    po[j] = ok ? (gh * W_ + gw) * 64 + 2 * cp : 0;
    if (ok) okm |= (1u << j);
  }

  const short8* wh8 = (const short8*)whi3;
  const short8* wl8 = (const short8*)wlo3;
  const int brBase = br * 1152;                 // set stride in short8 units

  float4v acc[2];
  acc[0] = (float4v)0.f;
  acc[1] = (float4v)0.f;

  for (int kcb = 0; kcb < 2; ++kcb) {
    unsigned sgh[NLD], sgl[NLD];
#pragma unroll
    for (int j = 0; j < NLD; ++j) {
      sgh[j] = *(const unsigned*)&ihi[(size_t)po[j] + kcb * 32];
      sgl[j] = *(const unsigned*)&ilo[(size_t)po[j] + kcb * 32];
    }
    __syncthreads();
#pragma unroll
    for (int j = 0; j < NLD; ++j) {
      int s = tid + 256 * j;
      if (s < 2880) {
        int sp = s >> 4, cp = s & 15;
        bool ok = (okm >> j) & 1;
        sT32[sp * 36 + cp] = ok ? sgh[j] : 0u;
        sT32[sp * 36 + 16 + cp] = ok ? sgl[j] : 0u;
      }
    }
    __syncthreads();

    short8 Ah[9], Al[9];
#pragma unroll
    for (int idx = 0; idx < 9; ++idx) {
      int fe = brBase + (kcb * 9 + idx) * 64 + lane;
      Ah[idx] = wh8[fe];
      Al[idx] = wl8[fe];
    }

#pragma unroll
    for (int r = 0; r < 4; ++r) {
      const int rr = 2 * wv + r;
      short8 Bh[3], Bl[3];
#pragma unroll
      for (int kx = 0; kx < 3; ++kx) {
        const unsigned short* p = &sT[(rr * 18 + n + kx) * 72 + 8 * q];
        Bh[kx] = *(const short8*)p;
        Bl[kx] = *(const short8*)(p + 32);
      }
#pragma unroll
      for (int ky = 0; ky < 3; ++ky) {
        const int pl = r - ky;
        if (pl >= 0 && pl < 2) {
#pragma unroll
          for (int kx = 0; kx < 3; ++kx) {
            const int idx = ky * 3 + kx;
            acc[pl] = __builtin_amdgcn_mfma_f32_16x16x32_bf16(Ah[idx], Bh[kx], acc[pl], 0, 0, 0);
            acc[pl] = __builtin_amdgcn_mfma_f32_16x16x32_bf16(Al[idx], Bh[kx], acc[pl], 0, 0, 0);
            acc[pl] = __builtin_amdgcn_mfma_f32_16x16x32_bf16(Ah[idx], Bl[kx], acc[pl], 0, 0, 0);
          }
        }
      }
    }
  }

  if (br == 0) {
    if (q < 2) {                                // co = 4q+r in [0,8)
      float4v bv = *(const float4v*)&b3e[4 * q];
#pragma unroll
      for (int pl = 0; pl < 2; ++pl) {
        int h = th0 + 2 * wv + pl;
#pragma unroll
        for (int r = 0; r < 4; ++r)
          xe[((size_t)(b * 8 + 4 * q + r) * H_ + h) * W_ + tw0 + n] = acc[pl][r] + bv[r];
      }
    }
  } else {
    if (q == 0) {                               // co 0 = log_temp
      float bt = b3t[0];
#pragma unroll
      for (int pl = 0; pl < 2; ++pl) {
        int h = th0 + 2 * wv + pl;
        ltm[(size_t)b * HW + h * W_ + tw0 + n] = acc[pl][0] + bt;
      }
    }
  }
}

// ---------------------------------------------------------------------------
// xcl: pack x (NCHW) to channels-last [b][pix][8] (dead h1t region).
// ---------------------------------------------------------------------------
__global__ __launch_bounds__(256) void xcl_k(const float* __restrict__ x,
                                             float* __restrict__ xcl) {
  int i = blockIdx.x * 256 + threadIdx.x;
  if (i >= B_ * HW) return;
  int b = i / HW, pix = i % HW;
  const float* xp = x + (size_t)b * CIN * HW + pix;
  float4v v0, v1;
#pragma unroll
  for (int c = 0; c < 4; ++c) v0[c] = xp[(size_t)c * HW];
#pragma unroll
  for (int c = 0; c < 4; ++c) v1[c] = xp[(size_t)(4 + c) * HW];
  *(float4v*)&xcl[(size_t)i * 8] = v0;
  *(float4v*)&xcl[(size_t)i * 8 + 4] = v1;
}

// ---------------------------------------------------------------------------
// prep: write pe row (from xe), reduce sq and lt (unchanged).
// ---------------------------------------------------------------------------
__global__ __launch_bounds__(256) void prep_k(const float* __restrict__ xe,
                                              const float* __restrict__ ltm,
                                              float* __restrict__ pe,
                                              float* __restrict__ lt,
                                              float* __restrict__ sq) {
  const int n = blockIdx.x, b = blockIdx.y;
  const int tid = threadIdx.x;
  const int wv = tid >> 6, lane = tid & 63;
  const int q1 = n / N2, q2 = n % N2;
  const int r0 = q1 * 5, c0 = q2 * 5;

  float s = 0.f;
  float* peR = pe + ((size_t)b * N_ + n) * D_;
#pragma unroll
  for (int j = 0; j < 4; ++j) {
    int d = tid + 256 * j;
    if (d < D_) {
      int c = d / 100;
      int rr = (d / 10) % 10;
      int cc = d % 10;
      size_t si = ((size_t)(b * 8 + c) * H_ + r0 + rr) * W_ + c0 + cc;
      float ve = xe[si];
      peR[d] = ve;
      s += ve * ve;
    }
  }
  float t = 0.f;
  if (tid < 100) t = ltm[(size_t)b * HW + (r0 + tid / 10) * W_ + c0 + tid % 10];

#pragma unroll
  for (int off = 32; off > 0; off >>= 1) {
    s += __shfl_xor(s, off);
    t += __shfl_xor(t, off);
  }
  __shared__ float rs[4], rt[4];
  if (lane == 0) { rs[wv] = s; rt[wv] = t; }
  __syncthreads();
  if (tid == 0) {
    sq[b * N_ + n] = rs[0] + rs[1] + rs[2] + rs[3];
    lt[b * N_ + n] = (rt[0] + rt[1] + rt[2] + rt[3]) * 0.01f;
  }
}

// ---------------------------------------------------------------------------
// attn stage 1 (unchanged).
// ---------------------------------------------------------------------------
__global__ __launch_bounds__(256) void attn_w_k(const float* __restrict__ pe,
                                                const float* __restrict__ lt,
                                                const float* __restrict__ sq,
                                                float* __restrict__ wk) {
  const int wv = threadIdx.x >> 6, lane = threadIdx.x & 63;
  const int ng = xcd_swz(blockIdx.x, (N_ + 3) / 4);
  const int n = ng * 4 + wv;
  if (n >= N_) return;
  const int b = blockIdx.y;
  const int q1 = n / N2, q2 = n % N2;

  const float* peB = pe + (size_t)b * N_ * D_;
  const float* qrow = peB + (size_t)n * D_;
  float q[13];
#pragma unroll
  for (int t = 0; t < 13; ++t) {
    int s = t * 64 + lane;
    q[t] = (s < D_) ? qrow[s] : 0.f;
  }

  const float sqn = sq[b * N_ + n];
  const float itemp = expf(-lt[b * N_ + n]);
  float gm = -INFINITY;

  for (int o1 = 0; o1 < 7; ++o1) {
    int c1 = clampi(q1 + o1 - 3, 0, N1 - 1);
    const float* rowb = peB + (size_t)(c1 * N2) * D_;
#pragma unroll
    for (int o2 = 0; o2 < 7; ++o2) {
      int c2 = clampi(q2 + o2 - 3, 0, N2 - 1);
      int cn = c1 * N2 + c2;
      const float* crow = rowb + (size_t)c2 * D_;
      float a = 0.f;
#pragma unroll
      for (int t = 0; t < 13; ++t) {
        float v;
        if (t < 12) v = crow[t * 64 + lane];
        else v = (lane < 32) ? crow[768 + lane] : 0.f;
        a += q[t] * v;
      }
#pragma unroll
      for (int off = 32; off > 0; off >>= 1) a += __shfl_xor(a, off);
      float Dv = -(sqn + sq[b * N_ + cn] - 2.f * a);
      float lg = (cn == n) ? -1e9f : Dv * itemp;
      const int m = o1 * 7 + o2;
      gm = (lane == m) ? lg : gm;
    }
  }

  float cur = (lane < M_) ? gm : -INFINITY;
  float* wrow = wk + (size_t)(b * N_ + n) * (M_ * K_);
#pragma unroll
  for (int k = 0; k < K_; ++k) {
    float mx = cur;
#pragma unroll
    for (int off = 32; off > 0; off >>= 1) mx = fmaxf(mx, __shfl_xor(mx, off));
    float e = (lane < M_) ? expf(cur - mx) : 0.f;
    float ssum = e;
#pragma unroll
    for (int off = 32; off > 0; off >>= 1) ssum += __shfl_xor(ssum, off);
    float w = e / ssum;
    if (lane < M_) wrow[lane * K_ + k] = w;
    cur += log1pf(-fminf(w, 1.f - 1e-6f));
  }
}

// ---------------------------------------------------------------------------
// foldpv R26: R23 structure (z=2, in-kernel S staging) + batched xv loads:
// 7 float4 loads per o1 row issued into a register array BEFORE the FMA
// block (R25's VGPR=80 showed the compiler hoisted almost nothing -> each
// (o1,o2) paid full L1/L2 latency serially). FMA order unchanged ->
// bitwise-identical. Offsets pre-scaled to element units.
// ---------------------------------------------------------------------------
__global__ __launch_bounds__(256) void foldpv_k(const float* __restrict__ xcl,
                                                const float* __restrict__ wk,
                                                float* __restrict__ out) {
  const int tile = xcd_swz(blockIdx.x, 196);
  const int b = blockIdx.y;
  const int c0 = blockIdx.z * 4;               // channels c0..c0+3
  const int t1 = tile / 14, t2 = tile % 14;
  const int ty0 = t1 * 16, tx0 = t2 * 16;
  const int tid = threadIdx.x;
  const int h = ty0 + (tid >> 4), w = tx0 + (tid & 15);
  const bool fast = (t1 >= 2 && t1 <= 11 && t2 >= 2 && t2 <= 11);

  __shared__ float smem[25 * 392];             // 39.2 KB (fast uses 16*392)

  const float* xclB = xcl + (size_t)b * HW * 8;
  const int pix = h * W_ + w;
  float* outB = out + (size_t)b * 64 * HW + pix;

  // x passthrough (4 channels per z)
  {
    float4v pv = *(const float4v*)&xclB[(size_t)pix * 8 + c0];
#pragma unroll
    for (int c = 0; c < 4; ++c) outB[(size_t)(c0 + c) * HW] = pv[c];
  }

  float acc[4][7];
#pragma unroll
  for (int c = 0; c < 4; ++c)
#pragma unroll
    for (int k = 0; k < 7; ++k) acc[c][k] = 0.f;

  if (fast) {
    const int cl1_0 = (ty0 - 5) / 5, cl2_0 = (tx0 - 5) / 5;
    // stage S = 0.25 * sum of 4 covering queries' wk rows, per cell
    for (int s = tid; s < 16 * 392; s += 256) {
      int cell = s / 392, r = s - cell * 392;
      int m = r >> 3, k = r & 7;
      float v = 0.f;
      if (k < 7) {
        int q1c = cl1_0 + (cell >> 2), q2c = cl2_0 + (cell & 3);
        size_t base = (size_t)(b * N_ + q1c * N2 + q2c) * (M_ * K_) + m * 7 + k;
        v = 0.25f * (wk[base] + wk[base + M_ * K_] +
                     wk[base + (size_t)N2 * (M_ * K_)] +
                     wk[base + (size_t)(N2 + 1) * (M_ * K_)]);
      }
      smem[s] = v;
    }
    __syncthreads();

    const int cl1 = (h - 5) / 5 - cl1_0, cl2 = (w - 5) / 5 - cl2_0;
    const float* sSp = smem + (cl1 * 4 + cl2) * 392;
    int roff[7], coff[7];
#pragma unroll
    for (int o = 0; o < 7; ++o) {
      roff[o] = (h + 5 * (o - 3)) * W_ * 8 + c0;    // element units
      coff[o] = (w + 5 * (o - 3)) * 8;
    }
#pragma unroll
    for (int o1 = 0; o1 < 7; ++o1) {
      float4v xvv[7];
#pragma unroll
      for (int o2 = 0; o2 < 7; ++o2)
        xvv[o2] = *(const float4v*)&xclB[(size_t)(roff[o1] + coff[o2])];
#pragma unroll
      for (int o2 = 0; o2 < 7; ++o2) {
        const float* sp = sSp + (o1 * 7 + o2) * 8;
        float4v w4 = *(const float4v*)sp;
        float2v w2 = *(const float2v*)(sp + 4);
        float w6 = sp[6];
#pragma unroll
        for (int c = 0; c < 4; ++c) {
          acc[c][0] += w4[0] * xvv[o2][c];
          acc[c][1] += w4[1] * xvv[o2][c];
          acc[c][2] += w4[2] * xvv[o2][c];
          acc[c][3] += w4[3] * xvv[o2][c];
          acc[c][4] += w2[0] * xvv[o2][c];
          acc[c][5] += w2[1] * xvv[o2][c];
          acc[c][6] += w6 * xvv[o2][c];
        }
      }
    }
#pragma unroll
    for (int k = 0; k < 7; ++k)
#pragma unroll
      for (int c = 0; c < 4; ++c)
        outB[(size_t)(8 + k * 8 + c0 + c) * HW] = acc[c][k];
    return;
  }

  // ---- slow path ----
  const int q1lo_t = max(0, (ty0 - 5) / 5), q1hi_t = min(N1 - 1, (ty0 + 15) / 5);
  const int q2lo_t = max(0, (tx0 - 5) / 5), q2hi_t = min(N2 - 1, (tx0 + 15) / 5);
  const int nq1 = q1hi_t - q1lo_t + 1, nq2 = q2hi_t - q2lo_t + 1;

  {
    const int tot = nq1 * nq2 * 392;
    for (int s = tid; s < tot; s += 256) {
      int lq = s / 392, r = s - lq * 392;
      int m = r >> 3, k = r & 7;
      int n = (q1lo_t + lq / nq2) * N2 + (q2lo_t + lq % nq2);
      smem[s] = (k < 7) ? wk[(size_t)(b * N_ + n) * (M_ * K_) + m * 7 + k] : 0.f;
    }
  }
  __syncthreads();

  const int q1lo = max(0, (h - 5) / 5), q1hi = min(N1 - 1, h / 5);
  const int q2lo = max(0, (w - 5) / 5), q2hi = min(N2 - 1, w / 5);

  int cnt = 0;
  for (int q1 = q1lo; q1 <= q1hi; ++q1) {
    const int ib = h - 5 * q1;
    const int lq1 = q1 - q1lo_t;
    for (int q2 = q2lo; q2 <= q2hi; ++q2) {
      ++cnt;
      const int jb = w - 5 * q2;
      const float* wq = smem + (lq1 * nq2 + (q2 - q2lo_t)) * 392;
      int ro[7], co[7];
#pragma unroll
      for (int o = 0; o < 7; ++o) {
        ro[o] = (clampi(q1 + o - 3, 0, N1 - 1) * 5 + ib) * W_ * 8 + c0;
        co[o] = (clampi(q2 + o - 3, 0, N2 - 1) * 5 + jb) * 8;
      }
#pragma unroll
      for (int o1 = 0; o1 < 7; ++o1) {
        float4v xvv[7];
#pragma unroll
        for (int o2 = 0; o2 < 7; ++o2)
          xvv[o2] = *(const float4v*)&xclB[(size_t)(ro[o1] + co[o2])];
#pragma unroll
        for (int o2 = 0; o2 < 7; ++o2) {
          const float* wp = wq + (o1 * 7 + o2) * 8;
          float4v w4 = *(const float4v*)wp;
          float2v w2 = *(const float2v*)(wp + 4);
          float w6 = wp[6];
#pragma unroll
          for (int c = 0; c < 4; ++c) {
            acc[c][0] += w4[0] * xvv[o2][c];
            acc[c][1] += w4[1] * xvv[o2][c];
            acc[c][2] += w4[2] * xvv[o2][c];
            acc[c][3] += w4[3] * xvv[o2][c];
            acc[c][4] += w2[0] * xvv[o2][c];
            acc[c][5] += w2[1] * xvv[o2][c];
            acc[c][6] += w6 * xvv[o2][c];
          }
        }
      }
    }
  }

  const float inv = (cnt > 0) ? 1.f / (float)cnt : 0.f;  // cnt in {0,1,2,4}
#pragma unroll
  for (int k = 0; k < 7; ++k)
#pragma unroll
    for (int c = 0; c < 4; ++c)
      outB[(size_t)(8 + k * 8 + c0 + c) * HW] = acc[c][k] * inv;
}

extern "C" void kernel_launch(void* const* d_in, const int* in_sizes, int n_in,
                              void* d_out, int out_size, void* d_ws,
                              size_t ws_size, hipStream_t stream) {
  const float* x   = (const float*)d_in[0];
  const float* w1e = (const float*)d_in[1];
  const float* b1e = (const float*)d_in[2];
  const float* w2e = (const float*)d_in[3];
  const float* b2e = (const float*)d_in[4];
  const float* w3e = (const float*)d_in[5];
  const float* b3e = (const float*)d_in[6];
  const float* w1t = (const float*)d_in[7];
  const float* b1t = (const float*)d_in[8];
  const float* w2t = (const float*)d_in[9];
  const float* b2t = (const float*)d_in[10];
  const float* w3t = (const float*)d_in[11];
  const float* b3t = (const float*)d_in[12];

  float* ws  = (float*)d_ws;
  float* out = (float*)d_out;

  unsigned short* h1e = (unsigned short*)(ws + OFF_H1E);   // bf16 channels-last
  unsigned short* h1t = (unsigned short*)(ws + OFF_H1T);
  unsigned short* h2ehi = (unsigned short*)(ws + OFF_H2E);   // channels-last hi/lo
  unsigned short* h2elo = h2ehi + (size_t)B_ * HW * 64;
  unsigned short* h2thi = (unsigned short*)(ws + OFF_H2T);
  unsigned short* h2tlo = h2thi + (size_t)B_ * HW * 64;
  float* wkb = ws + OFF_WK;
  float* xe  = ws + OFF_XE;
  float* ltm = ws + OFF_LTM;
  float* pe  = ws + OFF_PE;
  float* lt  = ws + OFF_LT;
  float* sqv = ws + OFF_SQ;
  unsigned short* whi  = (unsigned short*)(ws + OFF_XE);  // consumed before xe written
  unsigned short* wlo  = whi + WPREP_N;
  unsigned short* whi1 = wlo + WPREP_N;
  unsigned short* wlo1 = whi1 + WPREP1_N;
  unsigned short* whi3 = (unsigned short*)(ws + OFF_PE);  // consumed before pe written
  unsigned short* wlo3 = whi3 + 2 * WPREP3_N;
  float* xcl  = ws + OFF_XCL;  // channels-last x, dead h1t half (after conv2)

  // weight prep (conv1 + conv2 + conv3)
  wprep_k<<<(WPREP_TOT + 255) / 256, 256, 0, stream>>>(
      w2e, w2t, w1e, w1t, w3e, w3t, whi, wlo, whi1, wlo1, whi3, wlo3);
  // conv1 (8 -> 64, relu) via MFMA -> bf16-RNE channels-last
  conv1_k<<<dim3(196, 1, 4), 256, 0, stream>>>(x, whi1, wlo1, b1e, h1e, b1t, h1t);
  // conv2 (64 -> 64, relu) via MFMA (bf16 input, 2-term) -> hi/lo for conv3
  conv2_mfma_k<<<dim3(392, 1, 4), 256, 0, stream>>>(h1e, h1t, whi, wlo, b2e, b2t,
                                                    h2ehi, h2elo, h2thi, h2tlo);
  // pack x channels-last into the now-dead h1t region
  xcl_k<<<(B_ * HW + 255) / 256, 256, 0, stream>>>(x, xcl);
  // conv3 (64 -> 8 / 64 -> 1) via MFMA, 8x16 tiles, branch+batch in z
  conv3_mfma_k<<<dim3(392, 1, 4), 256, 0, stream>>>(h2ehi, h2elo, h2thi, h2tlo,
                                                    whi3, wlo3, b3e, b3t, xe, ltm);
  // patches + norms + log-temp means fused
  prep_k<<<dim3(N_, B_), 256, 0, stream>>>(xe, ltm, pe, lt, sqv);
  // attention stage 1: weights
  attn_w_k<<<dim3((N_ + 3) / 4, B_), 256, 0, stream>>>(pe, lt, sqv, wkb);
  // fused attn-PV + fold + passthrough (batched xv loads for ILP)
  foldpv_k<<<dim3(196, B_, 2), 256, 0, stream>>>(xcl, wkb, out);
}